// Round 13
// baseline (240.921 us; speedup 1.0000x reference)
//
#include <hip/hip_runtime.h>
#include <hip/hip_bf16.h>

constexpr int IN_DIM = 128;
constexpr int HID = 16;
constexpr int BSHIFT = 7;          // 128 dsts per bucket
constexpr int BSIZE = 1 << BSHIFT;
constexpr int CAP = 5120;          // slots per bucket (mean 4096, sigma 64)
constexpr int ECHUNK = 8192;       // edges per scatter block (24.2 KB LDS -> 6 blocks/CU)

typedef __attribute__((ext_vector_type(8))) short short8;
typedef __attribute__((ext_vector_type(4))) float f32x4;

static __device__ inline short f2bf(float x) {
    __hip_bfloat16 h = __float2bfloat16(x);
    return __builtin_bit_cast(short, h);
}
static __device__ inline float bf2f(unsigned short u) {
    unsigned int x = ((unsigned int)u) << 16;
    return __builtin_bit_cast(float, x);
}

__global__ __launch_bounds__(256) void k_init_curs(int* __restrict__ curs, int nbuck) {
    int b = blockIdx.x * 256 + threadIdx.x;
    if (b < nbuck) curs[b] = b * CAP;
}

// ---------- LDS counting-sort bin-scatter (standalone) ----------
__global__ __launch_bounds__(256) void k_scatter(
    const int* __restrict__ src, const int* __restrict__ dst, int E,
    int* __restrict__ curs, int* __restrict__ bin, int nbuck) {
    __shared__ int hist[1024];               // counts -> local cursor
    __shared__ int bstart[1024];             // scan -> diff (runbase - bstart)
    __shared__ unsigned short perm[ECHUNK];
    __shared__ int wsum[4];
    int t = threadIdx.x;
    int base = blockIdx.x * ECHUNK;
    int lim = min(ECHUNK, E - base);
    for (int i = t; i < 1024; i += 256) hist[i] = 0;
    __syncthreads();
    for (int i = t; i < lim; i += 256)
        atomicAdd(&hist[dst[base + i] >> BSHIFT], 1);
    __syncthreads();
    {
        int lane = t & 63, wv = t >> 6;
        int a0 = hist[4 * t], a1 = hist[4 * t + 1], a2 = hist[4 * t + 2], a3 = hist[4 * t + 3];
        int tot = a0 + a1 + a2 + a3;
        int run = tot;
#pragma unroll
        for (int o = 1; o < 64; o <<= 1) {
            int u = __shfl_up(run, o);
            if (lane >= o) run += u;
        }
        if (lane == 63) wsum[wv] = run;
        __syncthreads();
        int wbase = 0;
        for (int w = 0; w < wv; ++w) wbase += wsum[w];
        int excl = wbase + run - tot;
        bstart[4 * t] = excl;
        bstart[4 * t + 1] = excl + a0;
        bstart[4 * t + 2] = excl + a0 + a1;
        bstart[4 * t + 3] = excl + a0 + a1 + a2;
    }
    __syncthreads();
    // reserve global ranges; hist becomes local cursor; bstart becomes diff
    for (int bk = t; bk < 1024; bk += 256) {
        int c = hist[bk];
        int bs = bstart[bk];
        int rb = (c > 0 && bk < nbuck) ? atomicAdd(&curs[bk], c) : 0;
        hist[bk] = bs;            // cursor for perm build
        bstart[bk] = rb - bs;     // diff: global pos = diff + local sorted idx
    }
    __syncthreads();
    for (int i = t; i < lim; i += 256) {
        int d = dst[base + i];
        int pos = atomicAdd(&hist[d >> BSHIFT], 1);
        perm[pos] = (unsigned short)i;
    }
    __syncthreads();
    for (int i = t; i < lim; i += 256) {
        int idx = perm[i];
        int d = dst[base + idx];
        int s = src[base + idx];
        int bk = d >> BSHIFT;
        bin[bstart[bk] + i] = (s << BSHIFT) | (d & (BSIZE - 1));
    }
}

// ---------- MFMA ln_xw1 (standalone) + prep tail block ----------
__global__ __launch_bounds__(256) void k_ln(
    const float* __restrict__ x, const float* __restrict__ g, const float* __restrict__ b,
    const float* __restrict__ W1, float* __restrict__ y, int N, int lnBlocks,
    const float* __restrict__ W3, const float* __restrict__ eg, const float* __restrict__ eb,
    const float* __restrict__ b3, short* __restrict__ w3f, float* __restrict__ c12) {
    int bb = blockIdx.x;
    int t = threadIdx.x;
    if (bb >= lnBlocks) {
        // ---- prep block: w3f = bf16 frags of eg*W3; c1 = sum eg*W3; c2 = b3 + sum eb*W3 ----
        int l = t;
        if (l >= 64) return;
        int gg = l >> 4, r = l & 15;
#pragma unroll
        for (int kk = 0; kk < 2; ++kk) {
#pragma unroll
            for (int tt = 0; tt < 2; ++tt) {
                short8 frag;
#pragma unroll
                for (int j = 0; j < 8; ++j) {
                    int k = kk * 32 + gg * 8 + j;
                    int n = tt * 16 + r;
                    frag[j] = f2bf(eg[k] * W3[k * 32 + n]);
                }
                *(short8*)(w3f + (size_t)((kk * 2 + tt) * 64 + l) * 8) = frag;
            }
        }
        if (l < 32) {
            float s1 = 0.f, s2 = 0.f;
            for (int j = 0; j < 64; ++j) {
                s1 += eg[j] * W3[j * 32 + l];
                s2 += eb[j] * W3[j * 32 + l];
            }
            c12[l] = s1;
            c12[32 + l] = b3[l] + s2;
        }
        return;
    }
    // ---- ln_xw1 via MFMA: one wave = 16 nodes; y = LN(x)@W1 (UNSCALED, f32) ----
    int nb = (bb * 4 + (t >> 6)) * 16;
    if (nb >= N) return;
    int l = t & 63, gq = l >> 4, r = l & 15;
    int node = nb + r;
    bool ok = node < N;
    const float* xrow = x + (size_t)(ok ? node : 0) * IN_DIM + 8 * gq;
    float xv[4][8];
#pragma unroll
    for (int c = 0; c < 4; ++c) {
        f32x4 p0 = ok ? __builtin_nontemporal_load((const f32x4*)(xrow + 32 * c))
                      : (f32x4){0.f, 0.f, 0.f, 0.f};
        f32x4 p1 = ok ? __builtin_nontemporal_load((const f32x4*)(xrow + 32 * c + 4))
                      : (f32x4){0.f, 0.f, 0.f, 0.f};
        xv[c][0] = p0.x; xv[c][1] = p0.y; xv[c][2] = p0.z; xv[c][3] = p0.w;
        xv[c][4] = p1.x; xv[c][5] = p1.y; xv[c][6] = p1.z; xv[c][7] = p1.w;
    }
    float s = 0.f, q = 0.f;
#pragma unroll
    for (int c = 0; c < 4; ++c)
#pragma unroll
        for (int j = 0; j < 8; ++j) {
            s += xv[c][j];
            q = fmaf(xv[c][j], xv[c][j], q);
        }
    s += __shfl_xor(s, 16); s += __shfl_xor(s, 32);
    q += __shfl_xor(q, 16); q += __shfl_xor(q, 32);
    float mu = s * (1.0f / IN_DIM);
    float var = q * (1.0f / IN_DIM) - mu * mu;
    float rstd = rsqrtf(var + 1e-5f);
    f32x4 acc = {0.f, 0.f, 0.f, 0.f};
#pragma unroll
    for (int c = 0; c < 4; ++c) {
        const float* gp = g + 32 * c + 8 * gq;
        const float* bp = b + 32 * c + 8 * gq;
        const float* wp = W1 + (size_t)(32 * c + 8 * gq) * HID + r;
        short8 A, B;
#pragma unroll
        for (int j = 0; j < 8; ++j) {
            float xn = fmaf((xv[c][j] - mu) * rstd, gp[j], bp[j]);
            A[j] = f2bf(xn);
            B[j] = f2bf(wp[j * HID]);
        }
        acc = __builtin_amdgcn_mfma_f32_16x16x32_bf16(A, B, acc, 0, 0, 0);
    }
#pragma unroll
    for (int reg = 0; reg < 4; ++reg) {
        int n2 = nb + 4 * gq + reg;
        if (n2 < N) y[(size_t)n2 * HID + r] = acc[reg];
    }
}

// ---------- per-bucket: degree, dinv, offs, y-scale->bf16, csr fill ----------
__global__ __launch_bounds__(256) void k_bucket(const int* __restrict__ curs,
                                                const int* __restrict__ bin,
                                                float* __restrict__ dinv,
                                                int* __restrict__ offs,
                                                int* __restrict__ deg,
                                                const float* __restrict__ y,
                                                unsigned short* __restrict__ ybf,
                                                int* __restrict__ csr, int N) {
    __shared__ int cnt[BSIZE];
    __shared__ int scn[BSIZE];
    __shared__ float dl[BSIZE];
    int b = blockIdx.x;
    int lo = b * CAP;
    int hi = curs[b];
    if (threadIdx.x < BSIZE) cnt[threadIdx.x] = 0;
    __syncthreads();
    for (int i = lo + threadIdx.x; i < hi; i += 256)
        atomicAdd(&cnt[bin[i] & (BSIZE - 1)], 1);
    __syncthreads();
    if (threadIdx.x == 0) {
        int run = lo;
        for (int j = 0; j < BSIZE; ++j) { scn[j] = run; run += cnt[j]; }
    }
    __syncthreads();
    int d0 = b << BSHIFT;
    if (threadIdx.x < BSIZE) {
        int d = d0 + threadIdx.x;
        if (d < N) {
            int c = cnt[threadIdx.x];
            float di = rsqrtf((float)(c + 1));
            dl[threadIdx.x] = di;
            dinv[d] = di;
            offs[d] = scn[threadIdx.x];
            deg[d] = c;
        }
    }
    __syncthreads();
    for (int idx = threadIdx.x; idx < BSIZE * HID; idx += 256) {
        int d = d0 + (idx >> 4);
        if (d < N)
            ybf[(size_t)d * HID + (idx & 15)] =
                (unsigned short)f2bf(y[(size_t)d * HID + (idx & 15)] * dl[idx >> 4]);
    }
    for (int i = lo + threadIdx.x; i < hi; i += 256) {
        int v = bin[i];
        int pos = atomicAdd(&scn[v & (BSIZE - 1)], 1);
        csr[pos] = v >> BSHIFT;
    }
}

// ---------- gather1 + xw2 fused: y2 = bf16(dinv*(relu(b1+dinv*(sum))@W2)) ----------
__global__ __launch_bounds__(256) void k_gather_xw2(const unsigned short* __restrict__ y,
                                                    const float* __restrict__ dinv,
                                                    const float* __restrict__ bias,
                                                    const int* __restrict__ offs,
                                                    const int* __restrict__ deg,
                                                    const int* __restrict__ csr,
                                                    const float* __restrict__ W2,
                                                    unsigned short* __restrict__ y2, int N) {
    int t = blockIdx.x * 256 + threadIdx.x;
    int i = t >> 4, k = t & 15;
    if (i >= N) return;
    int j0 = offs[i], j1 = j0 + deg[i];
    float acc = bf2f(y[(size_t)i * HID + k]);
    int j = j0;
    for (; j + 4 <= j1; j += 4) {
        int s0 = __builtin_nontemporal_load(csr + j);
        int s1 = __builtin_nontemporal_load(csr + j + 1);
        int s2 = __builtin_nontemporal_load(csr + j + 2);
        int s3 = __builtin_nontemporal_load(csr + j + 3);
        float a0 = bf2f(y[(size_t)s0 * HID + k]);
        float a1 = bf2f(y[(size_t)s1 * HID + k]);
        float a2 = bf2f(y[(size_t)s2 * HID + k]);
        float a3 = bf2f(y[(size_t)s3 * HID + k]);
        acc += (a0 + a1) + (a2 + a3);
    }
    for (; j < j1; ++j) acc += bf2f(y[(size_t)__builtin_nontemporal_load(csr + j) * HID + k]);
    float di = dinv[i];
    float hk = fmaxf(bias[k] + di * acc, 0.0f);
    float acc2 = 0.f;
#pragma unroll
    for (int jj = 0; jj < 16; ++jj)
        acc2 = fmaf(__shfl(hk, jj, 16), W2[jj * 16 + k], acc2);
    y2[(size_t)i * HID + k] = (unsigned short)f2bf(di * acc2);
}

// ---------- gather2: h2 = bf16(relu(b2 + dinv*(sum y2))) ----------
__global__ __launch_bounds__(256) void k_gather(const unsigned short* __restrict__ y,
                                                const float* __restrict__ dinv,
                                                const float* __restrict__ bias,
                                                const int* __restrict__ offs,
                                                const int* __restrict__ deg,
                                                const int* __restrict__ csr,
                                                unsigned short* __restrict__ h, int N) {
    int t = blockIdx.x * 256 + threadIdx.x;
    int i = t >> 4, k = t & 15;
    if (i >= N) return;
    int j0 = offs[i], j1 = j0 + deg[i];
    float acc = bf2f(y[(size_t)i * HID + k]);
    int j = j0;
    for (; j + 4 <= j1; j += 4) {
        int s0 = __builtin_nontemporal_load(csr + j);
        int s1 = __builtin_nontemporal_load(csr + j + 1);
        int s2 = __builtin_nontemporal_load(csr + j + 2);
        int s3 = __builtin_nontemporal_load(csr + j + 3);
        float a0 = bf2f(y[(size_t)s0 * HID + k]);
        float a1 = bf2f(y[(size_t)s1 * HID + k]);
        float a2 = bf2f(y[(size_t)s2 * HID + k]);
        float a3 = bf2f(y[(size_t)s3 * HID + k]);
        acc += (a0 + a1) + (a2 + a3);
    }
    for (; j < j1; ++j) acc += bf2f(y[(size_t)__builtin_nontemporal_load(csr + j) * HID + k]);
    h[(size_t)i * HID + k] = (unsigned short)f2bf(fmaxf(bias[k] + dinv[i] * acc, 0.0f));
}

// ---------- Pair MLP via swapped MFMA: D[n][p]; pair = column = lane&15 ----------
__global__ __launch_bounds__(256) void k_pairs(const int* __restrict__ pa,
                                               const int* __restrict__ pb,
                                               const unsigned short* __restrict__ h2,
                                               const short* __restrict__ w3f,
                                               const float* __restrict__ c12,
                                               const float* __restrict__ W4,
                                               const float* __restrict__ b4,
                                               float* __restrict__ out,
                                               int P, int ntiles, int nwaves) {
    int wid = (blockIdx.x * 256 + threadIdx.x) >> 6;
    int l = threadIdx.x & 63;
    int g = l >> 4, r = l & 15;
    int h = g & 1;
    bool lo = (g < 2);

    short8 b00 = *(const short8*)(w3f + (size_t)(0 * 64 + l) * 8);
    short8 b01 = *(const short8*)(w3f + (size_t)(1 * 64 + l) * 8);
    short8 b10 = *(const short8*)(w3f + (size_t)(2 * 64 + l) * 8);
    short8 b11 = *(const short8*)(w3f + (size_t)(3 * 64 + l) * 8);
    float c1v[8], c2v[8], w4v[8];
#pragma unroll
    for (int reg = 0; reg < 4; ++reg) {
        c1v[reg]     = c12[4 * g + reg];
        c1v[4 + reg] = c12[16 + 4 * g + reg];
        c2v[reg]     = c12[32 + 4 * g + reg];
        c2v[4 + reg] = c12[48 + 4 * g + reg];
        w4v[reg]     = W4[4 * g + reg];
        w4v[4 + reg] = W4[16 + 4 * g + reg];
    }
    float b4v = b4[0];

    int tile = wid;
    short8 ubf = {0, 0, 0, 0, 0, 0, 0, 0}, vbf = ubf;
    if (tile < ntiles) {
        int p = tile * 16 + r;
        int pp = (p < P) ? p : 0;
        int ia = __builtin_nontemporal_load(pa + pp);
        int ib = __builtin_nontemporal_load(pb + pp);
        ubf = *(const short8*)(h2 + (size_t)ia * HID + 8 * h);
        vbf = *(const short8*)(h2 + (size_t)ib * HID + 8 * h);
    }
    for (; tile < ntiles; tile += nwaves) {
        int tn = tile + nwaves;
        short8 ubf_n = {0, 0, 0, 0, 0, 0, 0, 0}, vbf_n = ubf_n;
        if (tn < ntiles) {
            int p = tn * 16 + r;
            int pp = (p < P) ? p : 0;
            int ia = __builtin_nontemporal_load(pa + pp);
            int ib = __builtin_nontemporal_load(pb + pp);
            ubf_n = *(const short8*)(h2 + (size_t)ia * HID + 8 * h);
            vbf_n = *(const short8*)(h2 + (size_t)ib * HID + 8 * h);
        }
        float s = 0.f, q = 0.f;
        short8 A0, A1;
#pragma unroll
        for (int j = 0; j < 8; ++j) {
            float fu = bf2f((unsigned short)ubf[j]);
            float fv = bf2f((unsigned short)vbf[j]);
            float a0 = lo ? fu : fv;
            float a1 = lo ? fabsf(fu - fv) : fu * fv;
            s += a0 + a1;
            q = fmaf(a0, a0, q);
            q = fmaf(a1, a1, q);
            A0[j] = lo ? ubf[j] : vbf[j];
            A1[j] = f2bf(a1);
        }
        s += __shfl_xor(s, 16);
        s += __shfl_xor(s, 32);
        q += __shfl_xor(q, 16);
        q += __shfl_xor(q, 32);
        float mu = s * (1.0f / 64.0f);
        float var = q * (1.0f / 64.0f) - mu * mu;
        float rstd = rsqrtf(var + 1e-5f);

        f32x4 z = {0.f, 0.f, 0.f, 0.f};
        f32x4 d0 = __builtin_amdgcn_mfma_f32_16x16x32_bf16(b00, A0, z, 0, 0, 0);
        d0 = __builtin_amdgcn_mfma_f32_16x16x32_bf16(b10, A1, d0, 0, 0, 0);
        f32x4 d1 = __builtin_amdgcn_mfma_f32_16x16x32_bf16(b01, A0, z, 0, 0, 0);
        d1 = __builtin_amdgcn_mfma_f32_16x16x32_bf16(b11, A1, d1, 0, 0, 0);

        float pr = 0.f;
#pragma unroll
        for (int reg = 0; reg < 4; ++reg) {
            float e0 = fmaxf(fmaf(rstd, fmaf(-mu, c1v[reg], d0[reg]), c2v[reg]), 0.f);
            float e1 = fmaxf(fmaf(rstd, fmaf(-mu, c1v[4 + reg], d1[reg]), c2v[4 + reg]), 0.f);
            pr = fmaf(e0, w4v[reg], pr);
            pr = fmaf(e1, w4v[4 + reg], pr);
        }
        pr += __shfl_xor(pr, 16);
        pr += __shfl_xor(pr, 32);
        int p = tile * 16 + r;
        if (l < 16 && p < P) out[p] = pr + b4v;

        ubf = ubf_n;
        vbf = vbf_n;
    }
}

extern "C" void kernel_launch(void* const* d_in, const int* in_sizes, int n_in,
                              void* d_out, int out_size, void* d_ws, size_t ws_size,
                              hipStream_t stream) {
    const float* x    = (const float*)d_in[0];
    const int*   ei   = (const int*)d_in[1];
    const int*   ep   = (const int*)d_in[2];
    const float* ln_g = (const float*)d_in[3];
    const float* ln_b = (const float*)d_in[4];
    const float* W1   = (const float*)d_in[5];
    const float* b1   = (const float*)d_in[6];
    const float* W2   = (const float*)d_in[7];
    const float* b2   = (const float*)d_in[8];
    const float* eg   = (const float*)d_in[9];
    const float* eb   = (const float*)d_in[10];
    const float* W3   = (const float*)d_in[11];
    const float* b3   = (const float*)d_in[12];
    const float* W4   = (const float*)d_in[13];
    const float* b4   = (const float*)d_in[14];
    float* out = (float*)d_out;

    const int N = in_sizes[0] / IN_DIM;
    const int E = in_sizes[1] / 2;
    const int P = in_sizes[2] / 2;
    const int* src = ei;
    const int* dst = ei + E;
    const int* pa = ep;
    const int* pb = ep + P;

    auto cdiv = [](long a, long b) { return (int)((a + b - 1) / b); };
    const int NBUCK = cdiv(N, BSIZE);
    const size_t Na = ((size_t)N + 255) & ~(size_t)255;
    const size_t binSlots = (size_t)NBUCK * CAP;

    // workspace layout
    float*          dinv = (float*)d_ws;                   // Na
    int*            degA = (int*)(dinv + Na);              // Na
    int*            offs = degA + Na;                      // Na
    int*            curs = offs + Na;                      // 1024
    float*          y    = (float*)(curs + 1024);          // N*16 f32 (unscaled)
    unsigned short* ybf  = (unsigned short*)(y + (size_t)N * HID);  // N*16 bf16
    int*            csr  = (int*)(ybf + Na * HID);         // binSlots
    int*            bin  = csr + binSlots;                 // binSlots (dead after k_bucket)
    unsigned short* y2bf = (unsigned short*)bin;           // overlay on bin
    unsigned short* h2bf = y2bf + Na * HID;                // overlay on bin
    short*          w3f  = (short*)(bin + binSlots);       // 2048 shorts
    float*          c12  = (float*)(w3f + 2048);           // 64 floats

    const int nScat = cdiv(E, ECHUNK);    // 391
    const int lnBlocks = cdiv(N, 64);     // 1563

    k_init_curs<<<cdiv(NBUCK, 256), 256, 0, stream>>>(curs, NBUCK);
    k_scatter<<<nScat, 256, 0, stream>>>(src, dst, E, curs, bin, NBUCK);
    k_ln<<<lnBlocks + 1, 256, 0, stream>>>(x, ln_g, ln_b, W1, y, N, lnBlocks,
                                           W3, eg, eb, b3, w3f, c12);
    k_bucket<<<NBUCK, 256, 0, stream>>>(curs, bin, dinv, offs, degA, y, ybf, csr, N);
    k_gather_xw2<<<cdiv((long)N * 16, 256), 256, 0, stream>>>(ybf, dinv, b1, offs, degA, csr, W2, y2bf, N);
    k_gather<<<cdiv((long)N * 16, 256), 256, 0, stream>>>(y2bf, dinv, b2, offs, degA, csr, h2bf, N);

    const int ntiles = cdiv(P, 16);
    const int blocks = 2048;
    const int nwaves = blocks * 4;
    k_pairs<<<blocks, 256, 0, stream>>>(pa, pb, h2bf, w3f, c12, W4, b4, out, P, ntiles, nwaves);
}

// Round 14
// 231.124 us; speedup vs baseline: 1.0424x; 1.0424x over previous
//
#include <hip/hip_runtime.h>
#include <hip/hip_bf16.h>

constexpr int IN_DIM = 128;
constexpr int HID = 16;
constexpr int BSHIFT = 7;          // 128 dsts per bucket
constexpr int BSIZE = 1 << BSHIFT;
constexpr int CAP = 5120;          // slots per bucket (mean 4096, sigma 64)
constexpr int ECHUNK = 8192;       // edges per scatter block
constexpr int SBLK = 1024;         // scatter block threads (16 waves -> TLP for phases)

typedef __attribute__((ext_vector_type(8))) short short8;
typedef __attribute__((ext_vector_type(4))) float f32x4;

static __device__ inline short f2bf(float x) {
    __hip_bfloat16 h = __float2bfloat16(x);
    return __builtin_bit_cast(short, h);
}
static __device__ inline float bf2f(unsigned short u) {
    unsigned int x = ((unsigned int)u) << 16;
    return __builtin_bit_cast(float, x);
}

__global__ __launch_bounds__(256) void k_init_curs(int* __restrict__ curs, int nbuck) {
    int b = blockIdx.x * 256 + threadIdx.x;
    if (b < nbuck) curs[b] = b * CAP;
}

// ---------- LDS counting-sort bin-scatter (1024 threads: TLP for phase chain) ----------
__global__ __launch_bounds__(SBLK) void k_scatter(
    const int* __restrict__ src, const int* __restrict__ dst, int E,
    int* __restrict__ curs, int* __restrict__ bin, int nbuck) {
    __shared__ int hist[1024];               // counts -> local cursor
    __shared__ int bstart[1024];             // scan -> diff (runbase - bstart)
    __shared__ unsigned short perm[ECHUNK];
    __shared__ int wsum[SBLK / 64];
    int t = threadIdx.x;
    int base = blockIdx.x * ECHUNK;
    int lim = min(ECHUNK, E - base);
    hist[t] = 0;
    __syncthreads();
    for (int i = t; i < lim; i += SBLK)
        atomicAdd(&hist[dst[base + i] >> BSHIFT], 1);
    __syncthreads();
    {
        // exclusive scan of 1024 counts: 1 per thread, wave scan + cross-wave
        int lane = t & 63, wv = t >> 6;
        int v = hist[t];
        int run = v;
#pragma unroll
        for (int o = 1; o < 64; o <<= 1) {
            int u = __shfl_up(run, o);
            if (lane >= o) run += u;
        }
        if (lane == 63) wsum[wv] = run;
        __syncthreads();
        int wbase = 0;
        for (int w = 0; w < wv; ++w) wbase += wsum[w];
        bstart[t] = wbase + run - v;   // exclusive prefix
    }
    __syncthreads();
    // reserve global ranges; hist becomes local cursor; bstart becomes diff
    {
        int c = hist[t];
        int bs = bstart[t];
        int rb = (c > 0 && t < nbuck) ? atomicAdd(&curs[t], c) : 0;
        hist[t] = bs;            // cursor for perm build
        bstart[t] = rb - bs;     // diff: global pos = diff + local sorted idx
    }
    __syncthreads();
    for (int i = t; i < lim; i += SBLK) {
        int d = dst[base + i];
        int pos = atomicAdd(&hist[d >> BSHIFT], 1);
        perm[pos] = (unsigned short)i;
    }
    __syncthreads();
    for (int i = t; i < lim; i += SBLK) {
        int idx = perm[i];
        int d = dst[base + idx];
        int s = src[base + idx];
        int bk = d >> BSHIFT;
        bin[bstart[bk] + i] = (s << BSHIFT) | (d & (BSIZE - 1));
    }
}

// ---------- MFMA ln_xw1 (standalone) + prep tail block ----------
__global__ __launch_bounds__(256) void k_ln(
    const float* __restrict__ x, const float* __restrict__ g, const float* __restrict__ b,
    const float* __restrict__ W1, float* __restrict__ y, int N, int lnBlocks,
    const float* __restrict__ W3, const float* __restrict__ eg, const float* __restrict__ eb,
    const float* __restrict__ b3, short* __restrict__ w3f, float* __restrict__ c12) {
    int bb = blockIdx.x;
    int t = threadIdx.x;
    if (bb >= lnBlocks) {
        // ---- prep block ----
        int l = t;
        if (l >= 64) return;
        int gg = l >> 4, r = l & 15;
#pragma unroll
        for (int kk = 0; kk < 2; ++kk) {
#pragma unroll
            for (int tt = 0; tt < 2; ++tt) {
                short8 frag;
#pragma unroll
                for (int j = 0; j < 8; ++j) {
                    int k = kk * 32 + gg * 8 + j;
                    int n = tt * 16 + r;
                    frag[j] = f2bf(eg[k] * W3[k * 32 + n]);
                }
                *(short8*)(w3f + (size_t)((kk * 2 + tt) * 64 + l) * 8) = frag;
            }
        }
        if (l < 32) {
            float s1 = 0.f, s2 = 0.f;
            for (int j = 0; j < 64; ++j) {
                s1 += eg[j] * W3[j * 32 + l];
                s2 += eb[j] * W3[j * 32 + l];
            }
            c12[l] = s1;
            c12[32 + l] = b3[l] + s2;
        }
        return;
    }
    // ---- ln_xw1 via MFMA: one wave = 16 nodes; y = LN(x)@W1 (UNSCALED, f32) ----
    int nb = (bb * 4 + (t >> 6)) * 16;
    if (nb >= N) return;
    int l = t & 63, gq = l >> 4, r = l & 15;
    int node = nb + r;
    bool ok = node < N;
    const float* xrow = x + (size_t)(ok ? node : 0) * IN_DIM + 8 * gq;
    float xv[4][8];
#pragma unroll
    for (int c = 0; c < 4; ++c) {
        f32x4 p0 = ok ? __builtin_nontemporal_load((const f32x4*)(xrow + 32 * c))
                      : (f32x4){0.f, 0.f, 0.f, 0.f};
        f32x4 p1 = ok ? __builtin_nontemporal_load((const f32x4*)(xrow + 32 * c + 4))
                      : (f32x4){0.f, 0.f, 0.f, 0.f};
        xv[c][0] = p0.x; xv[c][1] = p0.y; xv[c][2] = p0.z; xv[c][3] = p0.w;
        xv[c][4] = p1.x; xv[c][5] = p1.y; xv[c][6] = p1.z; xv[c][7] = p1.w;
    }
    float s = 0.f, q = 0.f;
#pragma unroll
    for (int c = 0; c < 4; ++c)
#pragma unroll
        for (int j = 0; j < 8; ++j) {
            s += xv[c][j];
            q = fmaf(xv[c][j], xv[c][j], q);
        }
    s += __shfl_xor(s, 16); s += __shfl_xor(s, 32);
    q += __shfl_xor(q, 16); q += __shfl_xor(q, 32);
    float mu = s * (1.0f / IN_DIM);
    float var = q * (1.0f / IN_DIM) - mu * mu;
    float rstd = rsqrtf(var + 1e-5f);
    f32x4 acc = {0.f, 0.f, 0.f, 0.f};
#pragma unroll
    for (int c = 0; c < 4; ++c) {
        const float* gp = g + 32 * c + 8 * gq;
        const float* bp = b + 32 * c + 8 * gq;
        const float* wp = W1 + (size_t)(32 * c + 8 * gq) * HID + r;
        short8 A, B;
#pragma unroll
        for (int j = 0; j < 8; ++j) {
            float xn = fmaf((xv[c][j] - mu) * rstd, gp[j], bp[j]);
            A[j] = f2bf(xn);
            B[j] = f2bf(wp[j * HID]);
        }
        acc = __builtin_amdgcn_mfma_f32_16x16x32_bf16(A, B, acc, 0, 0, 0);
    }
#pragma unroll
    for (int reg = 0; reg < 4; ++reg) {
        int n2 = nb + 4 * gq + reg;
        if (n2 < N) y[(size_t)n2 * HID + r] = acc[reg];
    }
}

// ---------- per-bucket: degree, dinv, offs, y-scale->bf16, csr fill ----------
__global__ __launch_bounds__(256) void k_bucket(const int* __restrict__ curs,
                                                const int* __restrict__ bin,
                                                float* __restrict__ dinv,
                                                int* __restrict__ offs,
                                                int* __restrict__ deg,
                                                const float* __restrict__ y,
                                                unsigned short* __restrict__ ybf,
                                                int* __restrict__ csr, int N) {
    __shared__ int cnt[BSIZE];
    __shared__ int scn[BSIZE];
    __shared__ float dl[BSIZE];
    int b = blockIdx.x;
    int lo = b * CAP;
    int hi = curs[b];
    if (threadIdx.x < BSIZE) cnt[threadIdx.x] = 0;
    __syncthreads();
    for (int i = lo + threadIdx.x; i < hi; i += 256)
        atomicAdd(&cnt[bin[i] & (BSIZE - 1)], 1);
    __syncthreads();
    if (threadIdx.x == 0) {
        int run = lo;
        for (int j = 0; j < BSIZE; ++j) { scn[j] = run; run += cnt[j]; }
    }
    __syncthreads();
    int d0 = b << BSHIFT;
    if (threadIdx.x < BSIZE) {
        int d = d0 + threadIdx.x;
        if (d < N) {
            int c = cnt[threadIdx.x];
            float di = rsqrtf((float)(c + 1));
            dl[threadIdx.x] = di;
            dinv[d] = di;
            offs[d] = scn[threadIdx.x];
            deg[d] = c;
        }
    }
    __syncthreads();
    for (int idx = threadIdx.x; idx < BSIZE * HID; idx += 256) {
        int d = d0 + (idx >> 4);
        if (d < N)
            ybf[(size_t)d * HID + (idx & 15)] =
                (unsigned short)f2bf(y[(size_t)d * HID + (idx & 15)] * dl[idx >> 4]);
    }
    for (int i = lo + threadIdx.x; i < hi; i += 256) {
        int v = bin[i];
        int pos = atomicAdd(&scn[v & (BSIZE - 1)], 1);
        csr[pos] = v >> BSHIFT;
    }
}

// ---------- gather1 + xw2 fused: y2 = bf16(dinv*(relu(b1+dinv*(sum))@W2)) ----------
__global__ __launch_bounds__(256) void k_gather_xw2(const unsigned short* __restrict__ y,
                                                    const float* __restrict__ dinv,
                                                    const float* __restrict__ bias,
                                                    const int* __restrict__ offs,
                                                    const int* __restrict__ deg,
                                                    const int* __restrict__ csr,
                                                    const float* __restrict__ W2,
                                                    unsigned short* __restrict__ y2, int N) {
    int t = blockIdx.x * 256 + threadIdx.x;
    int i = t >> 4, k = t & 15;
    if (i >= N) return;
    int j0 = offs[i], j1 = j0 + deg[i];
    float acc = bf2f(y[(size_t)i * HID + k]);
    int j = j0;
    for (; j + 4 <= j1; j += 4) {
        int s0 = __builtin_nontemporal_load(csr + j);
        int s1 = __builtin_nontemporal_load(csr + j + 1);
        int s2 = __builtin_nontemporal_load(csr + j + 2);
        int s3 = __builtin_nontemporal_load(csr + j + 3);
        float a0 = bf2f(y[(size_t)s0 * HID + k]);
        float a1 = bf2f(y[(size_t)s1 * HID + k]);
        float a2 = bf2f(y[(size_t)s2 * HID + k]);
        float a3 = bf2f(y[(size_t)s3 * HID + k]);
        acc += (a0 + a1) + (a2 + a3);
    }
    for (; j < j1; ++j) acc += bf2f(y[(size_t)__builtin_nontemporal_load(csr + j) * HID + k]);
    float di = dinv[i];
    float hk = fmaxf(bias[k] + di * acc, 0.0f);
    float acc2 = 0.f;
#pragma unroll
    for (int jj = 0; jj < 16; ++jj)
        acc2 = fmaf(__shfl(hk, jj, 16), W2[jj * 16 + k], acc2);
    y2[(size_t)i * HID + k] = (unsigned short)f2bf(di * acc2);
}

// ---------- gather2: h2 = bf16(relu(b2 + dinv*(sum y2))) ----------
__global__ __launch_bounds__(256) void k_gather(const unsigned short* __restrict__ y,
                                                const float* __restrict__ dinv,
                                                const float* __restrict__ bias,
                                                const int* __restrict__ offs,
                                                const int* __restrict__ deg,
                                                const int* __restrict__ csr,
                                                unsigned short* __restrict__ h, int N) {
    int t = blockIdx.x * 256 + threadIdx.x;
    int i = t >> 4, k = t & 15;
    if (i >= N) return;
    int j0 = offs[i], j1 = j0 + deg[i];
    float acc = bf2f(y[(size_t)i * HID + k]);
    int j = j0;
    for (; j + 4 <= j1; j += 4) {
        int s0 = __builtin_nontemporal_load(csr + j);
        int s1 = __builtin_nontemporal_load(csr + j + 1);
        int s2 = __builtin_nontemporal_load(csr + j + 2);
        int s3 = __builtin_nontemporal_load(csr + j + 3);
        float a0 = bf2f(y[(size_t)s0 * HID + k]);
        float a1 = bf2f(y[(size_t)s1 * HID + k]);
        float a2 = bf2f(y[(size_t)s2 * HID + k]);
        float a3 = bf2f(y[(size_t)s3 * HID + k]);
        acc += (a0 + a1) + (a2 + a3);
    }
    for (; j < j1; ++j) acc += bf2f(y[(size_t)__builtin_nontemporal_load(csr + j) * HID + k]);
    h[(size_t)i * HID + k] = (unsigned short)f2bf(fmaxf(bias[k] + dinv[i] * acc, 0.0f));
}

// ---------- Pair MLP via swapped MFMA: D[n][p]; pair = column = lane&15 ----------
__global__ __launch_bounds__(256) void k_pairs(const int* __restrict__ pa,
                                               const int* __restrict__ pb,
                                               const unsigned short* __restrict__ h2,
                                               const short* __restrict__ w3f,
                                               const float* __restrict__ c12,
                                               const float* __restrict__ W4,
                                               const float* __restrict__ b4,
                                               float* __restrict__ out,
                                               int P, int ntiles, int nwaves) {
    int wid = (blockIdx.x * 256 + threadIdx.x) >> 6;
    int l = threadIdx.x & 63;
    int g = l >> 4, r = l & 15;
    int h = g & 1;
    bool lo = (g < 2);

    short8 b00 = *(const short8*)(w3f + (size_t)(0 * 64 + l) * 8);
    short8 b01 = *(const short8*)(w3f + (size_t)(1 * 64 + l) * 8);
    short8 b10 = *(const short8*)(w3f + (size_t)(2 * 64 + l) * 8);
    short8 b11 = *(const short8*)(w3f + (size_t)(3 * 64 + l) * 8);
    float c1v[8], c2v[8], w4v[8];
#pragma unroll
    for (int reg = 0; reg < 4; ++reg) {
        c1v[reg]     = c12[4 * g + reg];
        c1v[4 + reg] = c12[16 + 4 * g + reg];
        c2v[reg]     = c12[32 + 4 * g + reg];
        c2v[4 + reg] = c12[48 + 4 * g + reg];
        w4v[reg]     = W4[4 * g + reg];
        w4v[4 + reg] = W4[16 + 4 * g + reg];
    }
    float b4v = b4[0];

    int tile = wid;
    short8 ubf = {0, 0, 0, 0, 0, 0, 0, 0}, vbf = ubf;
    if (tile < ntiles) {
        int p = tile * 16 + r;
        int pp = (p < P) ? p : 0;
        int ia = __builtin_nontemporal_load(pa + pp);
        int ib = __builtin_nontemporal_load(pb + pp);
        ubf = *(const short8*)(h2 + (size_t)ia * HID + 8 * h);
        vbf = *(const short8*)(h2 + (size_t)ib * HID + 8 * h);
    }
    for (; tile < ntiles; tile += nwaves) {
        int tn = tile + nwaves;
        short8 ubf_n = {0, 0, 0, 0, 0, 0, 0, 0}, vbf_n = ubf_n;
        if (tn < ntiles) {
            int p = tn * 16 + r;
            int pp = (p < P) ? p : 0;
            int ia = __builtin_nontemporal_load(pa + pp);
            int ib = __builtin_nontemporal_load(pb + pp);
            ubf_n = *(const short8*)(h2 + (size_t)ia * HID + 8 * h);
            vbf_n = *(const short8*)(h2 + (size_t)ib * HID + 8 * h);
        }
        float s = 0.f, q = 0.f;
        short8 A0, A1;
#pragma unroll
        for (int j = 0; j < 8; ++j) {
            float fu = bf2f((unsigned short)ubf[j]);
            float fv = bf2f((unsigned short)vbf[j]);
            float a0 = lo ? fu : fv;
            float a1 = lo ? fabsf(fu - fv) : fu * fv;
            s += a0 + a1;
            q = fmaf(a0, a0, q);
            q = fmaf(a1, a1, q);
            A0[j] = lo ? ubf[j] : vbf[j];
            A1[j] = f2bf(a1);
        }
        s += __shfl_xor(s, 16);
        s += __shfl_xor(s, 32);
        q += __shfl_xor(q, 16);
        q += __shfl_xor(q, 32);
        float mu = s * (1.0f / 64.0f);
        float var = q * (1.0f / 64.0f) - mu * mu;
        float rstd = rsqrtf(var + 1e-5f);

        f32x4 z = {0.f, 0.f, 0.f, 0.f};
        f32x4 d0 = __builtin_amdgcn_mfma_f32_16x16x32_bf16(b00, A0, z, 0, 0, 0);
        d0 = __builtin_amdgcn_mfma_f32_16x16x32_bf16(b10, A1, d0, 0, 0, 0);
        f32x4 d1 = __builtin_amdgcn_mfma_f32_16x16x32_bf16(b01, A0, z, 0, 0, 0);
        d1 = __builtin_amdgcn_mfma_f32_16x16x32_bf16(b11, A1, d1, 0, 0, 0);

        float pr = 0.f;
#pragma unroll
        for (int reg = 0; reg < 4; ++reg) {
            float e0 = fmaxf(fmaf(rstd, fmaf(-mu, c1v[reg], d0[reg]), c2v[reg]), 0.f);
            float e1 = fmaxf(fmaf(rstd, fmaf(-mu, c1v[4 + reg], d1[reg]), c2v[4 + reg]), 0.f);
            pr = fmaf(e0, w4v[reg], pr);
            pr = fmaf(e1, w4v[4 + reg], pr);
        }
        pr += __shfl_xor(pr, 16);
        pr += __shfl_xor(pr, 32);
        int p = tile * 16 + r;
        if (l < 16 && p < P) out[p] = pr + b4v;

        ubf = ubf_n;
        vbf = vbf_n;
    }
}

extern "C" void kernel_launch(void* const* d_in, const int* in_sizes, int n_in,
                              void* d_out, int out_size, void* d_ws, size_t ws_size,
                              hipStream_t stream) {
    const float* x    = (const float*)d_in[0];
    const int*   ei   = (const int*)d_in[1];
    const int*   ep   = (const int*)d_in[2];
    const float* ln_g = (const float*)d_in[3];
    const float* ln_b = (const float*)d_in[4];
    const float* W1   = (const float*)d_in[5];
    const float* b1   = (const float*)d_in[6];
    const float* W2   = (const float*)d_in[7];
    const float* b2   = (const float*)d_in[8];
    const float* eg   = (const float*)d_in[9];
    const float* eb   = (const float*)d_in[10];
    const float* W3   = (const float*)d_in[11];
    const float* b3   = (const float*)d_in[12];
    const float* W4   = (const float*)d_in[13];
    const float* b4   = (const float*)d_in[14];
    float* out = (float*)d_out;

    const int N = in_sizes[0] / IN_DIM;
    const int E = in_sizes[1] / 2;
    const int P = in_sizes[2] / 2;
    const int* src = ei;
    const int* dst = ei + E;
    const int* pa = ep;
    const int* pb = ep + P;

    auto cdiv = [](long a, long b) { return (int)((a + b - 1) / b); };
    const int NBUCK = cdiv(N, BSIZE);
    const size_t Na = ((size_t)N + 255) & ~(size_t)255;
    const size_t binSlots = (size_t)NBUCK * CAP;

    // workspace layout
    float*          dinv = (float*)d_ws;                   // Na
    int*            degA = (int*)(dinv + Na);              // Na
    int*            offs = degA + Na;                      // Na
    int*            curs = offs + Na;                      // 1024
    float*          y    = (float*)(curs + 1024);          // N*16 f32 (unscaled)
    unsigned short* ybf  = (unsigned short*)(y + (size_t)N * HID);  // N*16 bf16
    int*            csr  = (int*)(ybf + Na * HID);         // binSlots
    int*            bin  = csr + binSlots;                 // binSlots (dead after k_bucket)
    unsigned short* y2bf = (unsigned short*)bin;           // overlay on bin
    unsigned short* h2bf = y2bf + Na * HID;                // overlay on bin
    short*          w3f  = (short*)(bin + binSlots);       // 2048 shorts
    float*          c12  = (float*)(w3f + 2048);           // 64 floats

    const int nScat = cdiv(E, ECHUNK);    // 391
    const int lnBlocks = cdiv(N, 64);     // 1563

    k_init_curs<<<cdiv(NBUCK, 256), 256, 0, stream>>>(curs, NBUCK);
    k_scatter<<<nScat, SBLK, 0, stream>>>(src, dst, E, curs, bin, NBUCK);
    k_ln<<<lnBlocks + 1, 256, 0, stream>>>(x, ln_g, ln_b, W1, y, N, lnBlocks,
                                           W3, eg, eb, b3, w3f, c12);
    k_bucket<<<NBUCK, 256, 0, stream>>>(curs, bin, dinv, offs, degA, y, ybf, csr, N);
    k_gather_xw2<<<cdiv((long)N * 16, 256), 256, 0, stream>>>(ybf, dinv, b1, offs, degA, csr, W2, y2bf, N);
    k_gather<<<cdiv((long)N * 16, 256), 256, 0, stream>>>(y2bf, dinv, b2, offs, degA, csr, h2bf, N);

    const int ntiles = cdiv(P, 16);
    const int blocks = 2048;
    const int nwaves = blocks * 4;
    k_pairs<<<blocks, 256, 0, stream>>>(pa, pb, h2bf, w3f, c12, W4, b4, out, P, ntiles, nwaves);
}

// Round 15
// 201.678 us; speedup vs baseline: 1.1946x; 1.1460x over previous
//
#include <hip/hip_runtime.h>
#include <hip/hip_bf16.h>

constexpr int IN_DIM = 128;
constexpr int HID = 16;
constexpr int BSHIFT = 7;          // 128 dsts per bucket
constexpr int BSIZE = 1 << BSHIFT;
constexpr int CAP = 5120;          // slots per bucket (mean 4096, sigma 64)
constexpr int ECHUNK = 8192;       // edges per scatter block
constexpr int SBLK = 1024;         // scatter block threads (16 waves -> TLP for phases)

typedef __attribute__((ext_vector_type(8))) short short8;
typedef __attribute__((ext_vector_type(4))) float f32x4;

static __device__ inline short f2bf(float x) {
    __hip_bfloat16 h = __float2bfloat16(x);
    return __builtin_bit_cast(short, h);
}
static __device__ inline float bf2f(unsigned short u) {
    unsigned int x = ((unsigned int)u) << 16;
    return __builtin_bit_cast(float, x);
}

__global__ __launch_bounds__(256) void k_init_curs(int* __restrict__ curs, int nbuck) {
    int b = blockIdx.x * 256 + threadIdx.x;
    if (b < nbuck) curs[b] = b * CAP;
}

// ---------- LDS counting-sort bin-scatter (1024 threads: TLP for phase chain) ----------
__global__ __launch_bounds__(SBLK) void k_scatter(
    const int* __restrict__ src, const int* __restrict__ dst, int E,
    int* __restrict__ curs, int* __restrict__ bin, int nbuck) {
    __shared__ int hist[1024];               // counts -> local cursor
    __shared__ int bstart[1024];             // scan -> diff (runbase - bstart)
    __shared__ unsigned short perm[ECHUNK];
    __shared__ int wsum[SBLK / 64];
    int t = threadIdx.x;
    int base = blockIdx.x * ECHUNK;
    int lim = min(ECHUNK, E - base);
    hist[t] = 0;
    __syncthreads();
    for (int i = t; i < lim; i += SBLK)
        atomicAdd(&hist[dst[base + i] >> BSHIFT], 1);
    __syncthreads();
    {
        int lane = t & 63, wv = t >> 6;
        int v = hist[t];
        int run = v;
#pragma unroll
        for (int o = 1; o < 64; o <<= 1) {
            int u = __shfl_up(run, o);
            if (lane >= o) run += u;
        }
        if (lane == 63) wsum[wv] = run;
        __syncthreads();
        int wbase = 0;
        for (int w = 0; w < wv; ++w) wbase += wsum[w];
        bstart[t] = wbase + run - v;   // exclusive prefix
    }
    __syncthreads();
    {
        int c = hist[t];
        int bs = bstart[t];
        int rb = (c > 0 && t < nbuck) ? atomicAdd(&curs[t], c) : 0;
        hist[t] = bs;            // cursor for perm build
        bstart[t] = rb - bs;     // diff: global pos = diff + local sorted idx
    }
    __syncthreads();
    for (int i = t; i < lim; i += SBLK) {
        int d = dst[base + i];
        int pos = atomicAdd(&hist[d >> BSHIFT], 1);
        perm[pos] = (unsigned short)i;
    }
    __syncthreads();
    for (int i = t; i < lim; i += SBLK) {
        int idx = perm[i];
        int d = dst[base + idx];
        int s = src[base + idx];
        int bk = d >> BSHIFT;
        bin[bstart[bk] + i] = (s << BSHIFT) | (d & (BSIZE - 1));
    }
}

// ---------- MFMA ln_xw1 (standalone) + prep tail block ----------
__global__ __launch_bounds__(256) void k_ln(
    const float* __restrict__ x, const float* __restrict__ g, const float* __restrict__ b,
    const float* __restrict__ W1, float* __restrict__ y, int N, int lnBlocks,
    const float* __restrict__ W3, const float* __restrict__ eg, const float* __restrict__ eb,
    const float* __restrict__ b3, short* __restrict__ w3f, float* __restrict__ c12) {
    int bb = blockIdx.x;
    int t = threadIdx.x;
    if (bb >= lnBlocks) {
        int l = t;
        if (l >= 64) return;
        int gg = l >> 4, r = l & 15;
#pragma unroll
        for (int kk = 0; kk < 2; ++kk) {
#pragma unroll
            for (int tt = 0; tt < 2; ++tt) {
                short8 frag;
#pragma unroll
                for (int j = 0; j < 8; ++j) {
                    int k = kk * 32 + gg * 8 + j;
                    int n = tt * 16 + r;
                    frag[j] = f2bf(eg[k] * W3[k * 32 + n]);
                }
                *(short8*)(w3f + (size_t)((kk * 2 + tt) * 64 + l) * 8) = frag;
            }
        }
        if (l < 32) {
            float s1 = 0.f, s2 = 0.f;
            for (int j = 0; j < 64; ++j) {
                s1 += eg[j] * W3[j * 32 + l];
                s2 += eb[j] * W3[j * 32 + l];
            }
            c12[l] = s1;
            c12[32 + l] = b3[l] + s2;
        }
        return;
    }
    int nb = (bb * 4 + (t >> 6)) * 16;
    if (nb >= N) return;
    int l = t & 63, gq = l >> 4, r = l & 15;
    int node = nb + r;
    bool ok = node < N;
    const float* xrow = x + (size_t)(ok ? node : 0) * IN_DIM + 8 * gq;
    float xv[4][8];
#pragma unroll
    for (int c = 0; c < 4; ++c) {
        f32x4 p0 = ok ? __builtin_nontemporal_load((const f32x4*)(xrow + 32 * c))
                      : (f32x4){0.f, 0.f, 0.f, 0.f};
        f32x4 p1 = ok ? __builtin_nontemporal_load((const f32x4*)(xrow + 32 * c + 4))
                      : (f32x4){0.f, 0.f, 0.f, 0.f};
        xv[c][0] = p0.x; xv[c][1] = p0.y; xv[c][2] = p0.z; xv[c][3] = p0.w;
        xv[c][4] = p1.x; xv[c][5] = p1.y; xv[c][6] = p1.z; xv[c][7] = p1.w;
    }
    float s = 0.f, q = 0.f;
#pragma unroll
    for (int c = 0; c < 4; ++c)
#pragma unroll
        for (int j = 0; j < 8; ++j) {
            s += xv[c][j];
            q = fmaf(xv[c][j], xv[c][j], q);
        }
    s += __shfl_xor(s, 16); s += __shfl_xor(s, 32);
    q += __shfl_xor(q, 16); q += __shfl_xor(q, 32);
    float mu = s * (1.0f / IN_DIM);
    float var = q * (1.0f / IN_DIM) - mu * mu;
    float rstd = rsqrtf(var + 1e-5f);
    f32x4 acc = {0.f, 0.f, 0.f, 0.f};
#pragma unroll
    for (int c = 0; c < 4; ++c) {
        const float* gp = g + 32 * c + 8 * gq;
        const float* bp = b + 32 * c + 8 * gq;
        const float* wp = W1 + (size_t)(32 * c + 8 * gq) * HID + r;
        short8 A, B;
#pragma unroll
        for (int j = 0; j < 8; ++j) {
            float xn = fmaf((xv[c][j] - mu) * rstd, gp[j], bp[j]);
            A[j] = f2bf(xn);
            B[j] = f2bf(wp[j * HID]);
        }
        acc = __builtin_amdgcn_mfma_f32_16x16x32_bf16(A, B, acc, 0, 0, 0);
    }
#pragma unroll
    for (int reg = 0; reg < 4; ++reg) {
        int n2 = nb + 4 * gq + reg;
        if (n2 < N) y[(size_t)n2 * HID + r] = acc[reg];
    }
}

// ---------- per-bucket: degree, dinv, offs, y-scale->bf16, csr fill ----------
__global__ __launch_bounds__(256) void k_bucket(const int* __restrict__ curs,
                                                const int* __restrict__ bin,
                                                float* __restrict__ dinv,
                                                int* __restrict__ offs,
                                                int* __restrict__ deg,
                                                const float* __restrict__ y,
                                                unsigned short* __restrict__ ybf,
                                                int* __restrict__ csr, int N) {
    __shared__ int cnt[BSIZE];
    __shared__ int scn[BSIZE];
    __shared__ float dl[BSIZE];
    int b = blockIdx.x;
    int lo = b * CAP;
    int hi = curs[b];
    if (threadIdx.x < BSIZE) cnt[threadIdx.x] = 0;
    __syncthreads();
    for (int i = lo + threadIdx.x; i < hi; i += 256)
        atomicAdd(&cnt[bin[i] & (BSIZE - 1)], 1);
    __syncthreads();
    if (threadIdx.x == 0) {
        int run = lo;
        for (int j = 0; j < BSIZE; ++j) { scn[j] = run; run += cnt[j]; }
    }
    __syncthreads();
    int d0 = b << BSHIFT;
    if (threadIdx.x < BSIZE) {
        int d = d0 + threadIdx.x;
        if (d < N) {
            int c = cnt[threadIdx.x];
            float di = rsqrtf((float)(c + 1));
            dl[threadIdx.x] = di;
            dinv[d] = di;
            offs[d] = scn[threadIdx.x];
            deg[d] = c;
        }
    }
    __syncthreads();
    for (int idx = threadIdx.x; idx < BSIZE * HID; idx += 256) {
        int d = d0 + (idx >> 4);
        if (d < N)
            ybf[(size_t)d * HID + (idx & 15)] =
                (unsigned short)f2bf(y[(size_t)d * HID + (idx & 15)] * dl[idx >> 4]);
    }
    for (int i = lo + threadIdx.x; i < hi; i += 256) {
        int v = bin[i];
        int pos = atomicAdd(&scn[v & (BSIZE - 1)], 1);
        csr[pos] = v >> BSHIFT;
    }
}

// ---------- gather1 + xw2 fused, 8-wide pipelined ----------
__global__ __launch_bounds__(256) void k_gather_xw2(const unsigned short* __restrict__ y,
                                                    const float* __restrict__ dinv,
                                                    const float* __restrict__ bias,
                                                    const int* __restrict__ offs,
                                                    const int* __restrict__ deg,
                                                    const int* __restrict__ csr,
                                                    const float* __restrict__ W2,
                                                    unsigned short* __restrict__ y2, int N) {
    int t = blockIdx.x * 256 + threadIdx.x;
    int i = t >> 4, k = t & 15;
    if (i >= N) return;
    int j0 = offs[i], j1 = j0 + deg[i];
    float acc = bf2f(y[(size_t)i * HID + k]);
    int j = j0;
    int c0, c1, c2, c3, c4, c5, c6, c7;
    if (j + 8 <= j1) {
        c0 = csr[j];     c1 = csr[j + 1]; c2 = csr[j + 2]; c3 = csr[j + 3];
        c4 = csr[j + 4]; c5 = csr[j + 5]; c6 = csr[j + 6]; c7 = csr[j + 7];
    }
    while (j + 8 <= j1) {
        int n0 = c0, n1 = c1, n2 = c2, n3 = c3, n4 = c4, n5 = c5, n6 = c6, n7 = c7;
        int jn = j + 8;
        if (jn + 8 <= j1) {   // prefetch next batch before consuming current
            c0 = csr[jn];     c1 = csr[jn + 1]; c2 = csr[jn + 2]; c3 = csr[jn + 3];
            c4 = csr[jn + 4]; c5 = csr[jn + 5]; c6 = csr[jn + 6]; c7 = csr[jn + 7];
        }
        float a0 = bf2f(y[(size_t)n0 * HID + k]);
        float a1 = bf2f(y[(size_t)n1 * HID + k]);
        float a2 = bf2f(y[(size_t)n2 * HID + k]);
        float a3 = bf2f(y[(size_t)n3 * HID + k]);
        float a4 = bf2f(y[(size_t)n4 * HID + k]);
        float a5 = bf2f(y[(size_t)n5 * HID + k]);
        float a6 = bf2f(y[(size_t)n6 * HID + k]);
        float a7 = bf2f(y[(size_t)n7 * HID + k]);
        acc += ((a0 + a1) + (a2 + a3)) + ((a4 + a5) + (a6 + a7));
        j = jn;
    }
    for (; j < j1; ++j) acc += bf2f(y[(size_t)csr[j] * HID + k]);
    float di = dinv[i];
    float hk = fmaxf(bias[k] + di * acc, 0.0f);
    float acc2 = 0.f;
#pragma unroll
    for (int jj = 0; jj < 16; ++jj)
        acc2 = fmaf(__shfl(hk, jj, 16), W2[jj * 16 + k], acc2);
    y2[(size_t)i * HID + k] = (unsigned short)f2bf(di * acc2);
}

// ---------- gather2, 8-wide pipelined: h2 = bf16(relu(b2 + dinv*(sum y2))) ----------
__global__ __launch_bounds__(256) void k_gather(const unsigned short* __restrict__ y,
                                                const float* __restrict__ dinv,
                                                const float* __restrict__ bias,
                                                const int* __restrict__ offs,
                                                const int* __restrict__ deg,
                                                const int* __restrict__ csr,
                                                unsigned short* __restrict__ h, int N) {
    int t = blockIdx.x * 256 + threadIdx.x;
    int i = t >> 4, k = t & 15;
    if (i >= N) return;
    int j0 = offs[i], j1 = j0 + deg[i];
    float acc = bf2f(y[(size_t)i * HID + k]);
    int j = j0;
    int c0, c1, c2, c3, c4, c5, c6, c7;
    if (j + 8 <= j1) {
        c0 = csr[j];     c1 = csr[j + 1]; c2 = csr[j + 2]; c3 = csr[j + 3];
        c4 = csr[j + 4]; c5 = csr[j + 5]; c6 = csr[j + 6]; c7 = csr[j + 7];
    }
    while (j + 8 <= j1) {
        int n0 = c0, n1 = c1, n2 = c2, n3 = c3, n4 = c4, n5 = c5, n6 = c6, n7 = c7;
        int jn = j + 8;
        if (jn + 8 <= j1) {
            c0 = csr[jn];     c1 = csr[jn + 1]; c2 = csr[jn + 2]; c3 = csr[jn + 3];
            c4 = csr[jn + 4]; c5 = csr[jn + 5]; c6 = csr[jn + 6]; c7 = csr[jn + 7];
        }
        float a0 = bf2f(y[(size_t)n0 * HID + k]);
        float a1 = bf2f(y[(size_t)n1 * HID + k]);
        float a2 = bf2f(y[(size_t)n2 * HID + k]);
        float a3 = bf2f(y[(size_t)n3 * HID + k]);
        float a4 = bf2f(y[(size_t)n4 * HID + k]);
        float a5 = bf2f(y[(size_t)n5 * HID + k]);
        float a6 = bf2f(y[(size_t)n6 * HID + k]);
        float a7 = bf2f(y[(size_t)n7 * HID + k]);
        acc += ((a0 + a1) + (a2 + a3)) + ((a4 + a5) + (a6 + a7));
        j = jn;
    }
    for (; j < j1; ++j) acc += bf2f(y[(size_t)csr[j] * HID + k]);
    h[(size_t)i * HID + k] = (unsigned short)f2bf(fmaxf(bias[k] + dinv[i] * acc, 0.0f));
}

// ---------- Pair MLP via swapped MFMA: D[n][p]; pair = column = lane&15 ----------
__global__ __launch_bounds__(256) void k_pairs(const int* __restrict__ pa,
                                               const int* __restrict__ pb,
                                               const unsigned short* __restrict__ h2,
                                               const short* __restrict__ w3f,
                                               const float* __restrict__ c12,
                                               const float* __restrict__ W4,
                                               const float* __restrict__ b4,
                                               float* __restrict__ out,
                                               int P, int ntiles, int nwaves) {
    int wid = (blockIdx.x * 256 + threadIdx.x) >> 6;
    int l = threadIdx.x & 63;
    int g = l >> 4, r = l & 15;
    int h = g & 1;
    bool lo = (g < 2);

    short8 b00 = *(const short8*)(w3f + (size_t)(0 * 64 + l) * 8);
    short8 b01 = *(const short8*)(w3f + (size_t)(1 * 64 + l) * 8);
    short8 b10 = *(const short8*)(w3f + (size_t)(2 * 64 + l) * 8);
    short8 b11 = *(const short8*)(w3f + (size_t)(3 * 64 + l) * 8);
    float c1v[8], c2v[8], w4v[8];
#pragma unroll
    for (int reg = 0; reg < 4; ++reg) {
        c1v[reg]     = c12[4 * g + reg];
        c1v[4 + reg] = c12[16 + 4 * g + reg];
        c2v[reg]     = c12[32 + 4 * g + reg];
        c2v[4 + reg] = c12[48 + 4 * g + reg];
        w4v[reg]     = W4[4 * g + reg];
        w4v[4 + reg] = W4[16 + 4 * g + reg];
    }
    float b4v = b4[0];

    int tile = wid;
    short8 ubf = {0, 0, 0, 0, 0, 0, 0, 0}, vbf = ubf;
    if (tile < ntiles) {
        int p = tile * 16 + r;
        int pp = (p < P) ? p : 0;
        int ia = __builtin_nontemporal_load(pa + pp);
        int ib = __builtin_nontemporal_load(pb + pp);
        ubf = *(const short8*)(h2 + (size_t)ia * HID + 8 * h);
        vbf = *(const short8*)(h2 + (size_t)ib * HID + 8 * h);
    }
    for (; tile < ntiles; tile += nwaves) {
        int tn = tile + nwaves;
        short8 ubf_n = {0, 0, 0, 0, 0, 0, 0, 0}, vbf_n = ubf_n;
        if (tn < ntiles) {
            int p = tn * 16 + r;
            int pp = (p < P) ? p : 0;
            int ia = __builtin_nontemporal_load(pa + pp);
            int ib = __builtin_nontemporal_load(pb + pp);
            ubf_n = *(const short8*)(h2 + (size_t)ia * HID + 8 * h);
            vbf_n = *(const short8*)(h2 + (size_t)ib * HID + 8 * h);
        }
        float s = 0.f, q = 0.f;
        short8 A0, A1;
#pragma unroll
        for (int j = 0; j < 8; ++j) {
            float fu = bf2f((unsigned short)ubf[j]);
            float fv = bf2f((unsigned short)vbf[j]);
            float a0 = lo ? fu : fv;
            float a1 = lo ? fabsf(fu - fv) : fu * fv;
            s += a0 + a1;
            q = fmaf(a0, a0, q);
            q = fmaf(a1, a1, q);
            A0[j] = lo ? ubf[j] : vbf[j];
            A1[j] = f2bf(a1);
        }
        s += __shfl_xor(s, 16);
        s += __shfl_xor(s, 32);
        q += __shfl_xor(q, 16);
        q += __shfl_xor(q, 32);
        float mu = s * (1.0f / 64.0f);
        float var = q * (1.0f / 64.0f) - mu * mu;
        float rstd = rsqrtf(var + 1e-5f);

        f32x4 z = {0.f, 0.f, 0.f, 0.f};
        f32x4 d0 = __builtin_amdgcn_mfma_f32_16x16x32_bf16(b00, A0, z, 0, 0, 0);
        d0 = __builtin_amdgcn_mfma_f32_16x16x32_bf16(b10, A1, d0, 0, 0, 0);
        f32x4 d1 = __builtin_amdgcn_mfma_f32_16x16x32_bf16(b01, A0, z, 0, 0, 0);
        d1 = __builtin_amdgcn_mfma_f32_16x16x32_bf16(b11, A1, d1, 0, 0, 0);

        float pr = 0.f;
#pragma unroll
        for (int reg = 0; reg < 4; ++reg) {
            float e0 = fmaxf(fmaf(rstd, fmaf(-mu, c1v[reg], d0[reg]), c2v[reg]), 0.f);
            float e1 = fmaxf(fmaf(rstd, fmaf(-mu, c1v[4 + reg], d1[reg]), c2v[4 + reg]), 0.f);
            pr = fmaf(e0, w4v[reg], pr);
            pr = fmaf(e1, w4v[4 + reg], pr);
        }
        pr += __shfl_xor(pr, 16);
        pr += __shfl_xor(pr, 32);
        int p = tile * 16 + r;
        if (l < 16 && p < P) out[p] = pr + b4v;

        ubf = ubf_n;
        vbf = vbf_n;
    }
}

extern "C" void kernel_launch(void* const* d_in, const int* in_sizes, int n_in,
                              void* d_out, int out_size, void* d_ws, size_t ws_size,
                              hipStream_t stream) {
    const float* x    = (const float*)d_in[0];
    const int*   ei   = (const int*)d_in[1];
    const int*   ep   = (const int*)d_in[2];
    const float* ln_g = (const float*)d_in[3];
    const float* ln_b = (const float*)d_in[4];
    const float* W1   = (const float*)d_in[5];
    const float* b1   = (const float*)d_in[6];
    const float* W2   = (const float*)d_in[7];
    const float* b2   = (const float*)d_in[8];
    const float* eg   = (const float*)d_in[9];
    const float* eb   = (const float*)d_in[10];
    const float* W3   = (const float*)d_in[11];
    const float* b3   = (const float*)d_in[12];
    const float* W4   = (const float*)d_in[13];
    const float* b4   = (const float*)d_in[14];
    float* out = (float*)d_out;

    const int N = in_sizes[0] / IN_DIM;
    const int E = in_sizes[1] / 2;
    const int P = in_sizes[2] / 2;
    const int* src = ei;
    const int* dst = ei + E;
    const int* pa = ep;
    const int* pb = ep + P;

    auto cdiv = [](long a, long b) { return (int)((a + b - 1) / b); };
    const int NBUCK = cdiv(N, BSIZE);
    const size_t Na = ((size_t)N + 255) & ~(size_t)255;
    const size_t binSlots = (size_t)NBUCK * CAP;

    // workspace layout
    float*          dinv = (float*)d_ws;                   // Na
    int*            degA = (int*)(dinv + Na);              // Na
    int*            offs = degA + Na;                      // Na
    int*            curs = offs + Na;                      // 1024
    float*          y    = (float*)(curs + 1024);          // N*16 f32 (unscaled)
    unsigned short* ybf  = (unsigned short*)(y + (size_t)N * HID);  // N*16 bf16
    int*            csr  = (int*)(ybf + Na * HID);         // binSlots
    int*            bin  = csr + binSlots;                 // binSlots (dead after k_bucket)
    unsigned short* y2bf = (unsigned short*)bin;           // overlay on bin
    unsigned short* h2bf = y2bf + Na * HID;                // overlay on bin
    short*          w3f  = (short*)(bin + binSlots);       // 2048 shorts
    float*          c12  = (float*)(w3f + 2048);           // 64 floats

    const int nScat = cdiv(E, ECHUNK);    // 391
    const int lnBlocks = cdiv(N, 64);     // 1563

    k_init_curs<<<cdiv(NBUCK, 256), 256, 0, stream>>>(curs, NBUCK);
    k_scatter<<<nScat, SBLK, 0, stream>>>(src, dst, E, curs, bin, NBUCK);
    k_ln<<<lnBlocks + 1, 256, 0, stream>>>(x, ln_g, ln_b, W1, y, N, lnBlocks,
                                           W3, eg, eb, b3, w3f, c12);
    k_bucket<<<NBUCK, 256, 0, stream>>>(curs, bin, dinv, offs, degA, y, ybf, csr, N);
    k_gather_xw2<<<cdiv((long)N * 16, 256), 256, 0, stream>>>(ybf, dinv, b1, offs, degA, csr, W2, y2bf, N);
    k_gather<<<cdiv((long)N * 16, 256), 256, 0, stream>>>(y2bf, dinv, b2, offs, degA, csr, h2bf, N);

    const int ntiles = cdiv(P, 16);
    const int blocks = 2048;
    const int nwaves = blocks * 4;
    k_pairs<<<blocks, 256, 0, stream>>>(pa, pb, h2bf, w3f, c12, W4, b4, out, P, ntiles, nwaves);
}

// Round 16
// 198.672 us; speedup vs baseline: 1.2127x; 1.0151x over previous
//
#include <hip/hip_runtime.h>
#include <hip/hip_bf16.h>

constexpr int IN_DIM = 128;
constexpr int HID = 16;
constexpr int BSHIFT = 7;          // 128 dsts per bucket
constexpr int BSIZE = 1 << BSHIFT;
constexpr int CAP = 5120;          // slots per bucket (mean 4096, sigma 64)
constexpr int ECHUNK = 8192;       // edges per scatter block
constexpr int SBLK = 1024;         // scatter/fat block threads

typedef __attribute__((ext_vector_type(8))) short short8;
typedef __attribute__((ext_vector_type(4))) float f32x4;

static __device__ inline short f2bf(float x) {
    __hip_bfloat16 h = __float2bfloat16(x);
    return __builtin_bit_cast(short, h);
}
static __device__ inline float bf2f(unsigned short u) {
    unsigned int x = ((unsigned int)u) << 16;
    return __builtin_bit_cast(float, x);
}

__global__ __launch_bounds__(256) void k_init_curs(int* __restrict__ curs, int nbuck) {
    int b = blockIdx.x * 256 + threadIdx.x;
    if (b < nbuck) curs[b] = b * CAP;
}

// ---------- FAT: LDS counting-sort bin-scatter ∥ MFMA ln_xw1 ∥ prep (all 1024t) ----------
__global__ __launch_bounds__(SBLK) void k_fat(
    const int* __restrict__ src, const int* __restrict__ dst, int E,
    int* __restrict__ curs, int* __restrict__ bin, int nbuck, int nScat,
    const float* __restrict__ x, const float* __restrict__ g, const float* __restrict__ b,
    const float* __restrict__ W1, float* __restrict__ y, int N, int lnBlocks,
    const float* __restrict__ W3, const float* __restrict__ eg, const float* __restrict__ eb,
    const float* __restrict__ b3, short* __restrict__ w3f, float* __restrict__ c12) {
    __shared__ int hist[1024];               // counts -> local cursor
    __shared__ int bstart[1024];             // scan -> diff (runbase - bstart)
    __shared__ unsigned short perm[ECHUNK];
    __shared__ int wsum[SBLK / 64];
    int bb = blockIdx.x;
    int t = threadIdx.x;
    if (bb < nScat) {
        // ---- scatter body ----
        int base = bb * ECHUNK;
        int lim = min(ECHUNK, E - base);
        hist[t] = 0;
        __syncthreads();
        for (int i = t; i < lim; i += SBLK)
            atomicAdd(&hist[dst[base + i] >> BSHIFT], 1);
        __syncthreads();
        {
            int lane = t & 63, wv = t >> 6;
            int v = hist[t];
            int run = v;
#pragma unroll
            for (int o = 1; o < 64; o <<= 1) {
                int u = __shfl_up(run, o);
                if (lane >= o) run += u;
            }
            if (lane == 63) wsum[wv] = run;
            __syncthreads();
            int wbase = 0;
            for (int w = 0; w < wv; ++w) wbase += wsum[w];
            bstart[t] = wbase + run - v;   // exclusive prefix
        }
        __syncthreads();
        {
            int c = hist[t];
            int bs = bstart[t];
            int rb = (c > 0 && t < nbuck) ? atomicAdd(&curs[t], c) : 0;
            hist[t] = bs;            // cursor for perm build
            bstart[t] = rb - bs;     // diff: global pos = diff + local sorted idx
        }
        __syncthreads();
        for (int i = t; i < lim; i += SBLK) {
            int d = dst[base + i];
            int pos = atomicAdd(&hist[d >> BSHIFT], 1);
            perm[pos] = (unsigned short)i;
        }
        __syncthreads();
        for (int i = t; i < lim; i += SBLK) {
            int idx = perm[i];
            int d = dst[base + idx];
            int s = src[base + idx];
            int bk = d >> BSHIFT;
            bin[bstart[bk] + i] = (s << BSHIFT) | (d & (BSIZE - 1));
        }
        return;
    }
    if (bb >= nScat + lnBlocks) {
        // ---- prep block ----
        int l = t;
        if (l >= 64) return;
        int gg = l >> 4, r = l & 15;
#pragma unroll
        for (int kk = 0; kk < 2; ++kk) {
#pragma unroll
            for (int tt = 0; tt < 2; ++tt) {
                short8 frag;
#pragma unroll
                for (int j = 0; j < 8; ++j) {
                    int k = kk * 32 + gg * 8 + j;
                    int n = tt * 16 + r;
                    frag[j] = f2bf(eg[k] * W3[k * 32 + n]);
                }
                *(short8*)(w3f + (size_t)((kk * 2 + tt) * 64 + l) * 8) = frag;
            }
        }
        if (l < 32) {
            float s1 = 0.f, s2 = 0.f;
            for (int j = 0; j < 64; ++j) {
                s1 += eg[j] * W3[j * 32 + l];
                s2 += eb[j] * W3[j * 32 + l];
            }
            c12[l] = s1;
            c12[32 + l] = b3[l] + s2;
        }
        return;
    }
    // ---- ln_xw1 via MFMA: 16 waves/block, one wave = 16 nodes ----
    {
        int wv = t >> 6;
        int nb = ((bb - nScat) * 16 + wv) * 16;
        if (nb >= N) return;
        int l = t & 63, gq = l >> 4, r = l & 15;
        int node = nb + r;
        bool ok = node < N;
        const float* xrow = x + (size_t)(ok ? node : 0) * IN_DIM + 8 * gq;
        float xv[4][8];
#pragma unroll
        for (int c = 0; c < 4; ++c) {
            f32x4 p0 = ok ? __builtin_nontemporal_load((const f32x4*)(xrow + 32 * c))
                          : (f32x4){0.f, 0.f, 0.f, 0.f};
            f32x4 p1 = ok ? __builtin_nontemporal_load((const f32x4*)(xrow + 32 * c + 4))
                          : (f32x4){0.f, 0.f, 0.f, 0.f};
            xv[c][0] = p0.x; xv[c][1] = p0.y; xv[c][2] = p0.z; xv[c][3] = p0.w;
            xv[c][4] = p1.x; xv[c][5] = p1.y; xv[c][6] = p1.z; xv[c][7] = p1.w;
        }
        float s = 0.f, q = 0.f;
#pragma unroll
        for (int c = 0; c < 4; ++c)
#pragma unroll
            for (int j = 0; j < 8; ++j) {
                s += xv[c][j];
                q = fmaf(xv[c][j], xv[c][j], q);
            }
        s += __shfl_xor(s, 16); s += __shfl_xor(s, 32);
        q += __shfl_xor(q, 16); q += __shfl_xor(q, 32);
        float mu = s * (1.0f / IN_DIM);
        float var = q * (1.0f / IN_DIM) - mu * mu;
        float rstd = rsqrtf(var + 1e-5f);
        f32x4 acc = {0.f, 0.f, 0.f, 0.f};
#pragma unroll
        for (int c = 0; c < 4; ++c) {
            const float* gp = g + 32 * c + 8 * gq;
            const float* bp = b + 32 * c + 8 * gq;
            const float* wp = W1 + (size_t)(32 * c + 8 * gq) * HID + r;
            short8 A, B;
#pragma unroll
            for (int j = 0; j < 8; ++j) {
                float xn = fmaf((xv[c][j] - mu) * rstd, gp[j], bp[j]);
                A[j] = f2bf(xn);
                B[j] = f2bf(wp[j * HID]);
            }
            acc = __builtin_amdgcn_mfma_f32_16x16x32_bf16(A, B, acc, 0, 0, 0);
        }
#pragma unroll
        for (int reg = 0; reg < 4; ++reg) {
            int n2 = nb + 4 * gq + reg;
            if (n2 < N) y[(size_t)n2 * HID + r] = acc[reg];
        }
    }
}

// ---------- per-bucket: degree, dinv, offs, y-scale->bf16, csr fill ----------
__global__ __launch_bounds__(256) void k_bucket(const int* __restrict__ curs,
                                                const int* __restrict__ bin,
                                                float* __restrict__ dinv,
                                                int* __restrict__ offs,
                                                int* __restrict__ deg,
                                                const float* __restrict__ y,
                                                unsigned short* __restrict__ ybf,
                                                int* __restrict__ csr, int N) {
    __shared__ int cnt[BSIZE];
    __shared__ int scn[BSIZE];
    __shared__ float dl[BSIZE];
    int b = blockIdx.x;
    int lo = b * CAP;
    int hi = curs[b];
    if (threadIdx.x < BSIZE) cnt[threadIdx.x] = 0;
    __syncthreads();
    for (int i = lo + threadIdx.x; i < hi; i += 256)
        atomicAdd(&cnt[bin[i] & (BSIZE - 1)], 1);
    __syncthreads();
    if (threadIdx.x == 0) {
        int run = lo;
        for (int j = 0; j < BSIZE; ++j) { scn[j] = run; run += cnt[j]; }
    }
    __syncthreads();
    int d0 = b << BSHIFT;
    if (threadIdx.x < BSIZE) {
        int d = d0 + threadIdx.x;
        if (d < N) {
            int c = cnt[threadIdx.x];
            float di = rsqrtf((float)(c + 1));
            dl[threadIdx.x] = di;
            dinv[d] = di;
            offs[d] = scn[threadIdx.x];
            deg[d] = c;
        }
    }
    __syncthreads();
    for (int idx = threadIdx.x; idx < BSIZE * HID; idx += 256) {
        int d = d0 + (idx >> 4);
        if (d < N)
            ybf[(size_t)d * HID + (idx & 15)] =
                (unsigned short)f2bf(y[(size_t)d * HID + (idx & 15)] * dl[idx >> 4]);
    }
    for (int i = lo + threadIdx.x; i < hi; i += 256) {
        int v = bin[i];
        int pos = atomicAdd(&scn[v & (BSIZE - 1)], 1);
        csr[pos] = v >> BSHIFT;
    }
}

// ---------- gather1 + xw2 fused, 8-wide pipelined ----------
__global__ __launch_bounds__(256) void k_gather_xw2(const unsigned short* __restrict__ y,
                                                    const float* __restrict__ dinv,
                                                    const float* __restrict__ bias,
                                                    const int* __restrict__ offs,
                                                    const int* __restrict__ deg,
                                                    const int* __restrict__ csr,
                                                    const float* __restrict__ W2,
                                                    unsigned short* __restrict__ y2, int N) {
    int t = blockIdx.x * 256 + threadIdx.x;
    int i = t >> 4, k = t & 15;
    if (i >= N) return;
    int j0 = offs[i], j1 = j0 + deg[i];
    float acc = bf2f(y[(size_t)i * HID + k]);
    int j = j0;
    int c0, c1, c2, c3, c4, c5, c6, c7;
    if (j + 8 <= j1) {
        c0 = csr[j];     c1 = csr[j + 1]; c2 = csr[j + 2]; c3 = csr[j + 3];
        c4 = csr[j + 4]; c5 = csr[j + 5]; c6 = csr[j + 6]; c7 = csr[j + 7];
    }
    while (j + 8 <= j1) {
        int n0 = c0, n1 = c1, n2 = c2, n3 = c3, n4 = c4, n5 = c5, n6 = c6, n7 = c7;
        int jn = j + 8;
        if (jn + 8 <= j1) {
            c0 = csr[jn];     c1 = csr[jn + 1]; c2 = csr[jn + 2]; c3 = csr[jn + 3];
            c4 = csr[jn + 4]; c5 = csr[jn + 5]; c6 = csr[jn + 6]; c7 = csr[jn + 7];
        }
        float a0 = bf2f(y[(size_t)n0 * HID + k]);
        float a1 = bf2f(y[(size_t)n1 * HID + k]);
        float a2 = bf2f(y[(size_t)n2 * HID + k]);
        float a3 = bf2f(y[(size_t)n3 * HID + k]);
        float a4 = bf2f(y[(size_t)n4 * HID + k]);
        float a5 = bf2f(y[(size_t)n5 * HID + k]);
        float a6 = bf2f(y[(size_t)n6 * HID + k]);
        float a7 = bf2f(y[(size_t)n7 * HID + k]);
        acc += ((a0 + a1) + (a2 + a3)) + ((a4 + a5) + (a6 + a7));
        j = jn;
    }
    for (; j < j1; ++j) acc += bf2f(y[(size_t)csr[j] * HID + k]);
    float di = dinv[i];
    float hk = fmaxf(bias[k] + di * acc, 0.0f);
    float acc2 = 0.f;
#pragma unroll
    for (int jj = 0; jj < 16; ++jj)
        acc2 = fmaf(__shfl(hk, jj, 16), W2[jj * 16 + k], acc2);
    y2[(size_t)i * HID + k] = (unsigned short)f2bf(di * acc2);
}

// ---------- gather2, 8-wide pipelined ----------
__global__ __launch_bounds__(256) void k_gather(const unsigned short* __restrict__ y,
                                                const float* __restrict__ dinv,
                                                const float* __restrict__ bias,
                                                const int* __restrict__ offs,
                                                const int* __restrict__ deg,
                                                const int* __restrict__ csr,
                                                unsigned short* __restrict__ h, int N) {
    int t = blockIdx.x * 256 + threadIdx.x;
    int i = t >> 4, k = t & 15;
    if (i >= N) return;
    int j0 = offs[i], j1 = j0 + deg[i];
    float acc = bf2f(y[(size_t)i * HID + k]);
    int j = j0;
    int c0, c1, c2, c3, c4, c5, c6, c7;
    if (j + 8 <= j1) {
        c0 = csr[j];     c1 = csr[j + 1]; c2 = csr[j + 2]; c3 = csr[j + 3];
        c4 = csr[j + 4]; c5 = csr[j + 5]; c6 = csr[j + 6]; c7 = csr[j + 7];
    }
    while (j + 8 <= j1) {
        int n0 = c0, n1 = c1, n2 = c2, n3 = c3, n4 = c4, n5 = c5, n6 = c6, n7 = c7;
        int jn = j + 8;
        if (jn + 8 <= j1) {
            c0 = csr[jn];     c1 = csr[jn + 1]; c2 = csr[jn + 2]; c3 = csr[jn + 3];
            c4 = csr[jn + 4]; c5 = csr[jn + 5]; c6 = csr[jn + 6]; c7 = csr[jn + 7];
        }
        float a0 = bf2f(y[(size_t)n0 * HID + k]);
        float a1 = bf2f(y[(size_t)n1 * HID + k]);
        float a2 = bf2f(y[(size_t)n2 * HID + k]);
        float a3 = bf2f(y[(size_t)n3 * HID + k]);
        float a4 = bf2f(y[(size_t)n4 * HID + k]);
        float a5 = bf2f(y[(size_t)n5 * HID + k]);
        float a6 = bf2f(y[(size_t)n6 * HID + k]);
        float a7 = bf2f(y[(size_t)n7 * HID + k]);
        acc += ((a0 + a1) + (a2 + a3)) + ((a4 + a5) + (a6 + a7));
        j = jn;
    }
    for (; j < j1; ++j) acc += bf2f(y[(size_t)csr[j] * HID + k]);
    h[(size_t)i * HID + k] = (unsigned short)f2bf(fmaxf(bias[k] + dinv[i] * acc, 0.0f));
}

// ---------- Pair MLP via swapped MFMA, 2-tile ILP ----------
__global__ __launch_bounds__(256) void k_pairs(const int* __restrict__ pa,
                                               const int* __restrict__ pb,
                                               const unsigned short* __restrict__ h2,
                                               const short* __restrict__ w3f,
                                               const float* __restrict__ c12,
                                               const float* __restrict__ W4,
                                               const float* __restrict__ b4,
                                               float* __restrict__ out,
                                               int P, int ntiles, int nwaves) {
    int wid = (blockIdx.x * 256 + threadIdx.x) >> 6;
    int l = threadIdx.x & 63;
    int g = l >> 4, r = l & 15;
    int h = g & 1;
    bool lo = (g < 2);

    short8 b00 = *(const short8*)(w3f + (size_t)(0 * 64 + l) * 8);
    short8 b01 = *(const short8*)(w3f + (size_t)(1 * 64 + l) * 8);
    short8 b10 = *(const short8*)(w3f + (size_t)(2 * 64 + l) * 8);
    short8 b11 = *(const short8*)(w3f + (size_t)(3 * 64 + l) * 8);
    float c1v[8], c2v[8], w4v[8];
#pragma unroll
    for (int reg = 0; reg < 4; ++reg) {
        c1v[reg]     = c12[4 * g + reg];
        c1v[4 + reg] = c12[16 + 4 * g + reg];
        c2v[reg]     = c12[32 + 4 * g + reg];
        c2v[4 + reg] = c12[48 + 4 * g + reg];
        w4v[reg]     = W4[4 * g + reg];
        w4v[4 + reg] = W4[16 + 4 * g + reg];
    }
    float b4v = b4[0];

    auto loadTile = [&](int tl, short8& u, short8& v) {
        u = (short8){0, 0, 0, 0, 0, 0, 0, 0};
        v = u;
        if (tl < ntiles) {
            int p = tl * 16 + r;
            int pp = (p < P) ? p : 0;
            int ia = __builtin_nontemporal_load(pa + pp);
            int ib = __builtin_nontemporal_load(pb + pp);
            u = *(const short8*)(h2 + (size_t)ia * HID + 8 * h);
            v = *(const short8*)(h2 + (size_t)ib * HID + 8 * h);
        }
    };
    auto compute = [&](int tl, short8 ubf, short8 vbf) {
        float s = 0.f, q = 0.f;
        short8 A0, A1;
#pragma unroll
        for (int j = 0; j < 8; ++j) {
            float fu = bf2f((unsigned short)ubf[j]);
            float fv = bf2f((unsigned short)vbf[j]);
            float a0 = lo ? fu : fv;
            float a1 = lo ? fabsf(fu - fv) : fu * fv;
            s += a0 + a1;
            q = fmaf(a0, a0, q);
            q = fmaf(a1, a1, q);
            A0[j] = lo ? ubf[j] : vbf[j];
            A1[j] = f2bf(a1);
        }
        s += __shfl_xor(s, 16);
        s += __shfl_xor(s, 32);
        q += __shfl_xor(q, 16);
        q += __shfl_xor(q, 32);
        float mu = s * (1.0f / 64.0f);
        float var = q * (1.0f / 64.0f) - mu * mu;
        float rstd = rsqrtf(var + 1e-5f);

        f32x4 z = {0.f, 0.f, 0.f, 0.f};
        f32x4 d0 = __builtin_amdgcn_mfma_f32_16x16x32_bf16(b00, A0, z, 0, 0, 0);
        d0 = __builtin_amdgcn_mfma_f32_16x16x32_bf16(b10, A1, d0, 0, 0, 0);
        f32x4 d1 = __builtin_amdgcn_mfma_f32_16x16x32_bf16(b01, A0, z, 0, 0, 0);
        d1 = __builtin_amdgcn_mfma_f32_16x16x32_bf16(b11, A1, d1, 0, 0, 0);

        float pr = 0.f;
#pragma unroll
        for (int reg = 0; reg < 4; ++reg) {
            float e0 = fmaxf(fmaf(rstd, fmaf(-mu, c1v[reg], d0[reg]), c2v[reg]), 0.f);
            float e1 = fmaxf(fmaf(rstd, fmaf(-mu, c1v[4 + reg], d1[reg]), c2v[4 + reg]), 0.f);
            pr = fmaf(e0, w4v[reg], pr);
            pr = fmaf(e1, w4v[4 + reg], pr);
        }
        pr += __shfl_xor(pr, 16);
        pr += __shfl_xor(pr, 32);
        int p = tl * 16 + r;
        if (l < 16 && p < P) out[p] = pr + b4v;
    };

    short8 uA, vA, uB, vB;
    loadTile(wid, uA, vA);
    loadTile(wid + nwaves, uB, vB);
    for (int tile = wid; tile < ntiles; tile += 2 * nwaves) {
        int tB = tile + nwaves;
        short8 uA2, vA2, uB2, vB2;
        loadTile(tile + 2 * nwaves, uA2, vA2);
        loadTile(tile + 3 * nwaves, uB2, vB2);
        compute(tile, uA, vA);
        if (tB < ntiles) compute(tB, uB, vB);
        uA = uA2; vA = vA2; uB = uB2; vB = vB2;
    }
}

extern "C" void kernel_launch(void* const* d_in, const int* in_sizes, int n_in,
                              void* d_out, int out_size, void* d_ws, size_t ws_size,
                              hipStream_t stream) {
    const float* x    = (const float*)d_in[0];
    const int*   ei   = (const int*)d_in[1];
    const int*   ep   = (const int*)d_in[2];
    const float* ln_g = (const float*)d_in[3];
    const float* ln_b = (const float*)d_in[4];
    const float* W1   = (const float*)d_in[5];
    const float* b1   = (const float*)d_in[6];
    const float* W2   = (const float*)d_in[7];
    const float* b2   = (const float*)d_in[8];
    const float* eg   = (const float*)d_in[9];
    const float* eb   = (const float*)d_in[10];
    const float* W3   = (const float*)d_in[11];
    const float* b3   = (const float*)d_in[12];
    const float* W4   = (const float*)d_in[13];
    const float* b4   = (const float*)d_in[14];
    float* out = (float*)d_out;

    const int N = in_sizes[0] / IN_DIM;
    const int E = in_sizes[1] / 2;
    const int P = in_sizes[2] / 2;
    const int* src = ei;
    const int* dst = ei + E;
    const int* pa = ep;
    const int* pb = ep + P;

    auto cdiv = [](long a, long b) { return (int)((a + b - 1) / b); };
    const int NBUCK = cdiv(N, BSIZE);
    const size_t Na = ((size_t)N + 255) & ~(size_t)255;
    const size_t binSlots = (size_t)NBUCK * CAP;

    // workspace layout
    float*          dinv = (float*)d_ws;                   // Na
    int*            degA = (int*)(dinv + Na);              // Na
    int*            offs = degA + Na;                      // Na
    int*            curs = offs + Na;                      // 1024
    float*          y    = (float*)(curs + 1024);          // N*16 f32 (unscaled)
    unsigned short* ybf  = (unsigned short*)(y + (size_t)N * HID);  // N*16 bf16
    int*            csr  = (int*)(ybf + Na * HID);         // binSlots
    int*            bin  = csr + binSlots;                 // binSlots (dead after k_bucket)
    unsigned short* y2bf = (unsigned short*)bin;           // overlay on bin
    unsigned short* h2bf = y2bf + Na * HID;                // overlay on bin
    short*          w3f  = (short*)(bin + binSlots);       // 2048 shorts
    float*          c12  = (float*)(w3f + 2048);           // 64 floats

    const int nScat = cdiv(E, ECHUNK);       // 391
    const int lnBlocks = cdiv(N, 256);       // 391 (16 waves x 16 nodes per block)

    k_init_curs<<<cdiv(NBUCK, 256), 256, 0, stream>>>(curs, NBUCK);
    k_fat<<<nScat + lnBlocks + 1, SBLK, 0, stream>>>(src, dst, E, curs, bin, NBUCK, nScat,
                                                     x, ln_g, ln_b, W1, y, N, lnBlocks,
                                                     W3, eg, eb, b3, w3f, c12);
    k_bucket<<<NBUCK, 256, 0, stream>>>(curs, bin, dinv, offs, degA, y, ybf, csr, N);
    k_gather_xw2<<<cdiv((long)N * 16, 256), 256, 0, stream>>>(ybf, dinv, b1, offs, degA, csr, W2, y2bf, N);
    k_gather<<<cdiv((long)N * 16, 256), 256, 0, stream>>>(y2bf, dinv, b2, offs, degA, csr, h2bf, N);

    const int ntiles = cdiv(P, 16);
    const int blocks = 2048;
    const int nwaves = blocks * 4;
    k_pairs<<<blocks, 256, 0, stream>>>(pa, pb, h2bf, w3f, c12, W4, b4, out, P, ntiles, nwaves);
}

// Round 17
// 183.325 us; speedup vs baseline: 1.3142x; 1.0837x over previous
//
#include <hip/hip_runtime.h>
#include <hip/hip_bf16.h>

constexpr int IN_DIM = 128;
constexpr int HID = 16;
constexpr int BSHIFT = 7;          // 128 dsts per bucket
constexpr int BSIZE = 1 << BSHIFT;
constexpr int CAP = 5120;          // slots per bucket (mean 4096, sigma 64)
constexpr int ECHUNK = 8192;       // edges per scatter block
constexpr int SBLK = 1024;         // scatter/fat block threads

typedef __attribute__((ext_vector_type(8))) short short8;
typedef __attribute__((ext_vector_type(4))) float f32x4;
typedef __attribute__((ext_vector_type(16))) float f32x16;

static __device__ inline short f2bf(float x) {
    __hip_bfloat16 h = __float2bfloat16(x);
    return __builtin_bit_cast(short, h);
}
static __device__ inline float bf2f(unsigned short u) {
    unsigned int x = ((unsigned int)u) << 16;
    return __builtin_bit_cast(float, x);
}

__global__ __launch_bounds__(256) void k_init_curs(int* __restrict__ curs, int nbuck) {
    int b = blockIdx.x * 256 + threadIdx.x;
    if (b < nbuck) curs[b] = b * CAP;
}

// ---------- FAT: LDS counting-sort bin-scatter ∥ MFMA ln_xw1 ∥ prep (all 1024t) ----------
__global__ __launch_bounds__(SBLK) void k_fat(
    const int* __restrict__ src, const int* __restrict__ dst, int E,
    int* __restrict__ curs, int* __restrict__ bin, int nbuck, int nScat,
    const float* __restrict__ x, const float* __restrict__ g, const float* __restrict__ b,
    const float* __restrict__ W1, float* __restrict__ y, int N, int lnBlocks,
    const float* __restrict__ W3, const float* __restrict__ eg, const float* __restrict__ eb,
    const float* __restrict__ b3, short* __restrict__ w3f, float* __restrict__ c12) {
    __shared__ int hist[1024];               // counts -> local cursor
    __shared__ int bstart[1024];             // scan -> diff (runbase - bstart)
    __shared__ unsigned short perm[ECHUNK];
    __shared__ int wsum[SBLK / 64];
    int bb = blockIdx.x;
    int t = threadIdx.x;
    if (bb < nScat) {
        // ---- scatter body ----
        int base = bb * ECHUNK;
        int lim = min(ECHUNK, E - base);
        hist[t] = 0;
        __syncthreads();
        for (int i = t; i < lim; i += SBLK)
            atomicAdd(&hist[dst[base + i] >> BSHIFT], 1);
        __syncthreads();
        {
            int lane = t & 63, wv = t >> 6;
            int v = hist[t];
            int run = v;
#pragma unroll
            for (int o = 1; o < 64; o <<= 1) {
                int u = __shfl_up(run, o);
                if (lane >= o) run += u;
            }
            if (lane == 63) wsum[wv] = run;
            __syncthreads();
            int wbase = 0;
            for (int w = 0; w < wv; ++w) wbase += wsum[w];
            bstart[t] = wbase + run - v;   // exclusive prefix
        }
        __syncthreads();
        {
            int c = hist[t];
            int bs = bstart[t];
            int rb = (c > 0 && t < nbuck) ? atomicAdd(&curs[t], c) : 0;
            hist[t] = bs;            // cursor for perm build
            bstart[t] = rb - bs;     // diff: global pos = diff + local sorted idx
        }
        __syncthreads();
        for (int i = t; i < lim; i += SBLK) {
            int d = dst[base + i];
            int pos = atomicAdd(&hist[d >> BSHIFT], 1);
            perm[pos] = (unsigned short)i;
        }
        __syncthreads();
        for (int i = t; i < lim; i += SBLK) {
            int idx = perm[i];
            int d = dst[base + idx];
            int s = src[base + idx];
            int bk = d >> BSHIFT;
            bin[bstart[bk] + i] = (s << BSHIFT) | (d & (BSIZE - 1));
        }
        return;
    }
    if (bb >= nScat + lnBlocks) {
        // ---- prep block: W3 frags in 32x32x16 A-layout: A[row=n=l&31][k=(l>>5)*8+j] ----
        int l = t;
        if (l >= 64) return;
        int n = l & 31, kh = l >> 5;
#pragma unroll
        for (int c = 0; c < 4; ++c) {
            short8 frag;
#pragma unroll
            for (int j = 0; j < 8; ++j) {
                int k = c * 16 + kh * 8 + j;
                frag[j] = f2bf(eg[k] * W3[k * 32 + n]);
            }
            *(short8*)(w3f + (size_t)(c * 64 + l) * 8) = frag;
        }
        if (l < 32) {
            float s1 = 0.f, s2 = 0.f;
            for (int j = 0; j < 64; ++j) {
                s1 += eg[j] * W3[j * 32 + l];
                s2 += eb[j] * W3[j * 32 + l];
            }
            c12[l] = s1;
            c12[32 + l] = b3[l] + s2;
        }
        return;
    }
    // ---- ln_xw1 via MFMA: 16 waves/block, one wave = 16 nodes ----
    {
        int wv = t >> 6;
        int nb = ((bb - nScat) * 16 + wv) * 16;
        if (nb >= N) return;
        int l = t & 63, gq = l >> 4, r = l & 15;
        int node = nb + r;
        bool ok = node < N;
        const float* xrow = x + (size_t)(ok ? node : 0) * IN_DIM + 8 * gq;
        float xv[4][8];
#pragma unroll
        for (int c = 0; c < 4; ++c) {
            f32x4 p0 = ok ? __builtin_nontemporal_load((const f32x4*)(xrow + 32 * c))
                          : (f32x4){0.f, 0.f, 0.f, 0.f};
            f32x4 p1 = ok ? __builtin_nontemporal_load((const f32x4*)(xrow + 32 * c + 4))
                          : (f32x4){0.f, 0.f, 0.f, 0.f};
            xv[c][0] = p0.x; xv[c][1] = p0.y; xv[c][2] = p0.z; xv[c][3] = p0.w;
            xv[c][4] = p1.x; xv[c][5] = p1.y; xv[c][6] = p1.z; xv[c][7] = p1.w;
        }
        float s = 0.f, q = 0.f;
#pragma unroll
        for (int c = 0; c < 4; ++c)
#pragma unroll
            for (int j = 0; j < 8; ++j) {
                s += xv[c][j];
                q = fmaf(xv[c][j], xv[c][j], q);
            }
        s += __shfl_xor(s, 16); s += __shfl_xor(s, 32);
        q += __shfl_xor(q, 16); q += __shfl_xor(q, 32);
        float mu = s * (1.0f / IN_DIM);
        float var = q * (1.0f / IN_DIM) - mu * mu;
        float rstd = rsqrtf(var + 1e-5f);
        f32x4 acc = {0.f, 0.f, 0.f, 0.f};
#pragma unroll
        for (int c = 0; c < 4; ++c) {
            const float* gp = g + 32 * c + 8 * gq;
            const float* bp = b + 32 * c + 8 * gq;
            const float* wp = W1 + (size_t)(32 * c + 8 * gq) * HID + r;
            short8 A, B;
#pragma unroll
            for (int j = 0; j < 8; ++j) {
                float xn = fmaf((xv[c][j] - mu) * rstd, gp[j], bp[j]);
                A[j] = f2bf(xn);
                B[j] = f2bf(wp[j * HID]);
            }
            acc = __builtin_amdgcn_mfma_f32_16x16x32_bf16(A, B, acc, 0, 0, 0);
        }
#pragma unroll
        for (int reg = 0; reg < 4; ++reg) {
            int n2 = nb + 4 * gq + reg;
            if (n2 < N) y[(size_t)n2 * HID + r] = acc[reg];
        }
    }
}

// ---------- per-bucket: degree, dinv, offs, y-scale->bf16, csr fill ----------
__global__ __launch_bounds__(256) void k_bucket(const int* __restrict__ curs,
                                                const int* __restrict__ bin,
                                                float* __restrict__ dinv,
                                                int* __restrict__ offs,
                                                int* __restrict__ deg,
                                                const float* __restrict__ y,
                                                unsigned short* __restrict__ ybf,
                                                int* __restrict__ csr, int N) {
    __shared__ int cnt[BSIZE];
    __shared__ int scn[BSIZE];
    __shared__ float dl[BSIZE];
    int b = blockIdx.x;
    int lo = b * CAP;
    int hi = curs[b];
    if (threadIdx.x < BSIZE) cnt[threadIdx.x] = 0;
    __syncthreads();
    for (int i = lo + threadIdx.x; i < hi; i += 256)
        atomicAdd(&cnt[bin[i] & (BSIZE - 1)], 1);
    __syncthreads();
    if (threadIdx.x == 0) {
        int run = lo;
        for (int j = 0; j < BSIZE; ++j) { scn[j] = run; run += cnt[j]; }
    }
    __syncthreads();
    int d0 = b << BSHIFT;
    if (threadIdx.x < BSIZE) {
        int d = d0 + threadIdx.x;
        if (d < N) {
            int c = cnt[threadIdx.x];
            float di = rsqrtf((float)(c + 1));
            dl[threadIdx.x] = di;
            dinv[d] = di;
            offs[d] = scn[threadIdx.x];
            deg[d] = c;
        }
    }
    __syncthreads();
    for (int idx = threadIdx.x; idx < BSIZE * HID; idx += 256) {
        int d = d0 + (idx >> 4);
        if (d < N)
            ybf[(size_t)d * HID + (idx & 15)] =
                (unsigned short)f2bf(y[(size_t)d * HID + (idx & 15)] * dl[idx >> 4]);
    }
    for (int i = lo + threadIdx.x; i < hi; i += 256) {
        int v = bin[i];
        int pos = atomicAdd(&scn[v & (BSIZE - 1)], 1);
        csr[pos] = v >> BSHIFT;
    }
}

// ---------- gather1 + xw2 fused, 8-wide pipelined ----------
__global__ __launch_bounds__(256) void k_gather_xw2(const unsigned short* __restrict__ y,
                                                    const float* __restrict__ dinv,
                                                    const float* __restrict__ bias,
                                                    const int* __restrict__ offs,
                                                    const int* __restrict__ deg,
                                                    const int* __restrict__ csr,
                                                    const float* __restrict__ W2,
                                                    unsigned short* __restrict__ y2, int N) {
    int t = blockIdx.x * 256 + threadIdx.x;
    int i = t >> 4, k = t & 15;
    if (i >= N) return;
    int j0 = offs[i], j1 = j0 + deg[i];
    float acc = bf2f(y[(size_t)i * HID + k]);
    int j = j0;
    int c0, c1, c2, c3, c4, c5, c6, c7;
    if (j + 8 <= j1) {
        c0 = csr[j];     c1 = csr[j + 1]; c2 = csr[j + 2]; c3 = csr[j + 3];
        c4 = csr[j + 4]; c5 = csr[j + 5]; c6 = csr[j + 6]; c7 = csr[j + 7];
    }
    while (j + 8 <= j1) {
        int n0 = c0, n1 = c1, n2 = c2, n3 = c3, n4 = c4, n5 = c5, n6 = c6, n7 = c7;
        int jn = j + 8;
        if (jn + 8 <= j1) {
            c0 = csr[jn];     c1 = csr[jn + 1]; c2 = csr[jn + 2]; c3 = csr[jn + 3];
            c4 = csr[jn + 4]; c5 = csr[jn + 5]; c6 = csr[jn + 6]; c7 = csr[jn + 7];
        }
        float a0 = bf2f(y[(size_t)n0 * HID + k]);
        float a1 = bf2f(y[(size_t)n1 * HID + k]);
        float a2 = bf2f(y[(size_t)n2 * HID + k]);
        float a3 = bf2f(y[(size_t)n3 * HID + k]);
        float a4 = bf2f(y[(size_t)n4 * HID + k]);
        float a5 = bf2f(y[(size_t)n5 * HID + k]);
        float a6 = bf2f(y[(size_t)n6 * HID + k]);
        float a7 = bf2f(y[(size_t)n7 * HID + k]);
        acc += ((a0 + a1) + (a2 + a3)) + ((a4 + a5) + (a6 + a7));
        j = jn;
    }
    for (; j < j1; ++j) acc += bf2f(y[(size_t)csr[j] * HID + k]);
    float di = dinv[i];
    float hk = fmaxf(bias[k] + di * acc, 0.0f);
    float acc2 = 0.f;
#pragma unroll
    for (int jj = 0; jj < 16; ++jj)
        acc2 = fmaf(__shfl(hk, jj, 16), W2[jj * 16 + k], acc2);
    y2[(size_t)i * HID + k] = (unsigned short)f2bf(di * acc2);
}

// ---------- gather2, 8-wide pipelined ----------
__global__ __launch_bounds__(256) void k_gather(const unsigned short* __restrict__ y,
                                                const float* __restrict__ dinv,
                                                const float* __restrict__ bias,
                                                const int* __restrict__ offs,
                                                const int* __restrict__ deg,
                                                const int* __restrict__ csr,
                                                unsigned short* __restrict__ h, int N) {
    int t = blockIdx.x * 256 + threadIdx.x;
    int i = t >> 4, k = t & 15;
    if (i >= N) return;
    int j0 = offs[i], j1 = j0 + deg[i];
    float acc = bf2f(y[(size_t)i * HID + k]);
    int j = j0;
    int c0, c1, c2, c3, c4, c5, c6, c7;
    if (j + 8 <= j1) {
        c0 = csr[j];     c1 = csr[j + 1]; c2 = csr[j + 2]; c3 = csr[j + 3];
        c4 = csr[j + 4]; c5 = csr[j + 5]; c6 = csr[j + 6]; c7 = csr[j + 7];
    }
    while (j + 8 <= j1) {
        int n0 = c0, n1 = c1, n2 = c2, n3 = c3, n4 = c4, n5 = c5, n6 = c6, n7 = c7;
        int jn = j + 8;
        if (jn + 8 <= j1) {
            c0 = csr[jn];     c1 = csr[jn + 1]; c2 = csr[jn + 2]; c3 = csr[jn + 3];
            c4 = csr[jn + 4]; c5 = csr[jn + 5]; c6 = csr[jn + 6]; c7 = csr[jn + 7];
        }
        float a0 = bf2f(y[(size_t)n0 * HID + k]);
        float a1 = bf2f(y[(size_t)n1 * HID + k]);
        float a2 = bf2f(y[(size_t)n2 * HID + k]);
        float a3 = bf2f(y[(size_t)n3 * HID + k]);
        float a4 = bf2f(y[(size_t)n4 * HID + k]);
        float a5 = bf2f(y[(size_t)n5 * HID + k]);
        float a6 = bf2f(y[(size_t)n6 * HID + k]);
        float a7 = bf2f(y[(size_t)n7 * HID + k]);
        acc += ((a0 + a1) + (a2 + a3)) + ((a4 + a5) + (a6 + a7));
        j = jn;
    }
    for (; j < j1; ++j) acc += bf2f(y[(size_t)csr[j] * HID + k]);
    h[(size_t)i * HID + k] = (unsigned short)f2bf(fmaxf(bias[k] + dinv[i] * acc, 0.0f));
}

// ---------- Pair MLP via swapped 32x32x16 MFMA: one wave = 32 pairs ----------
// D[n][p]: pair p = lane&31, channel n = (reg&3)+8*(reg>>2)+4*(lane>>5).
// B-frags are the feat blocks directly: chunk c in {u, v, |u-v|, u*v}, lane
// (p, kh=lane>>5) supplies elements k = c*16 + kh*8 + j.
__global__ __launch_bounds__(256) void k_pairs(const int* __restrict__ pa,
                                               const int* __restrict__ pb,
                                               const unsigned short* __restrict__ h2,
                                               const short* __restrict__ w3f,
                                               const float* __restrict__ c12,
                                               const float* __restrict__ W4,
                                               const float* __restrict__ b4,
                                               float* __restrict__ out,
                                               int P, int ntiles, int nwaves) {
    int wid = (blockIdx.x * 256 + threadIdx.x) >> 6;
    int l = threadIdx.x & 63;
    int p32 = l & 31;      // pair within tile
    int kh = l >> 5;       // k-half selector

    short8 wf0 = *(const short8*)(w3f + (size_t)(0 * 64 + l) * 8);
    short8 wf1 = *(const short8*)(w3f + (size_t)(1 * 64 + l) * 8);
    short8 wf2 = *(const short8*)(w3f + (size_t)(2 * 64 + l) * 8);
    short8 wf3 = *(const short8*)(w3f + (size_t)(3 * 64 + l) * 8);
    float c1v[16], c2v[16], w4v[16];
#pragma unroll
    for (int reg = 0; reg < 16; ++reg) {
        int n = (reg & 3) + 8 * (reg >> 2) + 4 * kh;
        c1v[reg] = c12[n];
        c2v[reg] = c12[32 + n];
        w4v[reg] = W4[n];
    }
    float b4v = b4[0];

    auto loadTile = [&](int tl, short8& u, short8& v) {
        u = (short8){0, 0, 0, 0, 0, 0, 0, 0};
        v = u;
        if (tl < ntiles) {
            int p = tl * 32 + p32;
            int pp = (p < P) ? p : 0;
            int ia = __builtin_nontemporal_load(pa + pp);
            int ib = __builtin_nontemporal_load(pb + pp);
            u = *(const short8*)(h2 + (size_t)ia * HID + 8 * kh);
            v = *(const short8*)(h2 + (size_t)ib * HID + 8 * kh);
        }
    };

    short8 ubf, vbf;
    loadTile(wid, ubf, vbf);
    for (int tile = wid; tile < ntiles; tile += nwaves) {
        short8 ubf_n, vbf_n;
        loadTile(tile + nwaves, ubf_n, vbf_n);

        // feat prep: B2 = |u-v|, B3 = u*v; stats over lane's 16 feat elements
        float s = 0.f, q = 0.f;
        short8 B2, B3;
#pragma unroll
        for (int j = 0; j < 8; ++j) {
            float fu = bf2f((unsigned short)ubf[j]);
            float fv = bf2f((unsigned short)vbf[j]);
            float a2 = fabsf(fu - fv);
            float a3 = fu * fv;
            s += (fu + fv) + (a2 + a3);
            q = fmaf(fu, fu, q);
            q = fmaf(fv, fv, q);
            q = fmaf(a2, a2, q);
            q = fmaf(a3, a3, q);
            B2[j] = f2bf(a2);
            B3[j] = f2bf(a3);
        }
        s += __shfl_xor(s, 32);
        q += __shfl_xor(q, 32);
        float mu = s * (1.0f / 64.0f);
        float var = q * (1.0f / 64.0f) - mu * mu;
        float rstd = rsqrtf(var + 1e-5f);

        f32x16 d = {0.f, 0.f, 0.f, 0.f, 0.f, 0.f, 0.f, 0.f,
                    0.f, 0.f, 0.f, 0.f, 0.f, 0.f, 0.f, 0.f};
        d = __builtin_amdgcn_mfma_f32_32x32x16_bf16(wf0, ubf, d, 0, 0, 0);   // k 0-15: u
        d = __builtin_amdgcn_mfma_f32_32x32x16_bf16(wf1, vbf, d, 0, 0, 0);   // k 16-31: v
        d = __builtin_amdgcn_mfma_f32_32x32x16_bf16(wf2, B2, d, 0, 0, 0);    // k 32-47: |u-v|
        d = __builtin_amdgcn_mfma_f32_32x32x16_bf16(wf3, B3, d, 0, 0, 0);    // k 48-63: u*v

        float pr = 0.f;
#pragma unroll
        for (int reg = 0; reg < 16; ++reg) {
            float e = fmaxf(fmaf(rstd, fmaf(-mu, c1v[reg], d[reg]), c2v[reg]), 0.f);
            pr = fmaf(e, w4v[reg], pr);
        }
        pr += __shfl_xor(pr, 32);
        int p = tile * 32 + p32;
        if (l < 32 && p < P) out[p] = pr + b4v;

        ubf = ubf_n;
        vbf = vbf_n;
    }
}

extern "C" void kernel_launch(void* const* d_in, const int* in_sizes, int n_in,
                              void* d_out, int out_size, void* d_ws, size_t ws_size,
                              hipStream_t stream) {
    const float* x    = (const float*)d_in[0];
    const int*   ei   = (const int*)d_in[1];
    const int*   ep   = (const int*)d_in[2];
    const float* ln_g = (const float*)d_in[3];
    const float* ln_b = (const float*)d_in[4];
    const float* W1   = (const float*)d_in[5];
    const float* b1   = (const float*)d_in[6];
    const float* W2   = (const float*)d_in[7];
    const float* b2   = (const float*)d_in[8];
    const float* eg   = (const float*)d_in[9];
    const float* eb   = (const float*)d_in[10];
    const float* W3   = (const float*)d_in[11];
    const float* b3   = (const float*)d_in[12];
    const float* W4   = (const float*)d_in[13];
    const float* b4   = (const float*)d_in[14];
    float* out = (float*)d_out;

    const int N = in_sizes[0] / IN_DIM;
    const int E = in_sizes[1] / 2;
    const int P = in_sizes[2] / 2;
    const int* src = ei;
    const int* dst = ei + E;
    const int* pa = ep;
    const int* pb = ep + P;

    auto cdiv = [](long a, long b) { return (int)((a + b - 1) / b); };
    const int NBUCK = cdiv(N, BSIZE);
    const size_t Na = ((size_t)N + 255) & ~(size_t)255;
    const size_t binSlots = (size_t)NBUCK * CAP;

    // workspace layout
    float*          dinv = (float*)d_ws;                   // Na
    int*            degA = (int*)(dinv + Na);              // Na
    int*            offs = degA + Na;                      // Na
    int*            curs = offs + Na;                      // 1024
    float*          y    = (float*)(curs + 1024);          // N*16 f32 (unscaled)
    unsigned short* ybf  = (unsigned short*)(y + (size_t)N * HID);  // N*16 bf16
    int*            csr  = (int*)(ybf + Na * HID);         // binSlots
    int*            bin  = csr + binSlots;                 // binSlots (dead after k_bucket)
    unsigned short* y2bf = (unsigned short*)bin;           // overlay on bin
    unsigned short* h2bf = y2bf + Na * HID;                // overlay on bin
    short*          w3f  = (short*)(bin + binSlots);       // 2048 shorts
    float*          c12  = (float*)(w3f + 2048);           // 64 floats

    const int nScat = cdiv(E, ECHUNK);       // 391
    const int lnBlocks = cdiv(N, 256);       // 391 (16 waves x 16 nodes per block)

    k_init_curs<<<cdiv(NBUCK, 256), 256, 0, stream>>>(curs, NBUCK);
    k_fat<<<nScat + lnBlocks + 1, SBLK, 0, stream>>>(src, dst, E, curs, bin, NBUCK, nScat,
                                                     x, ln_g, ln_b, W1, y, N, lnBlocks,
                                                     W3, eg, eb, b3, w3f, c12);
    k_bucket<<<NBUCK, 256, 0, stream>>>(curs, bin, dinv, offs, degA, y, ybf, csr, N);
    k_gather_xw2<<<cdiv((long)N * 16, 256), 256, 0, stream>>>(ybf, dinv, b1, offs, degA, csr, W2, y2bf, N);
    k_gather<<<cdiv((long)N * 16, 256), 256, 0, stream>>>(y2bf, dinv, b2, offs, degA, csr, h2bf, N);

    const int ntiles = cdiv(P, 32);
    const int blocks = 2048;
    const int nwaves = blocks * 4;
    k_pairs<<<blocks, 256, 0, stream>>>(pa, pb, h2bf, w3f, c12, W4, b4, out, P, ntiles, nwaves);
}

// Round 18
// 172.099 us; speedup vs baseline: 1.3999x; 1.0652x over previous
//
#include <hip/hip_runtime.h>
#include <hip/hip_bf16.h>

constexpr int IN_DIM = 128;
constexpr int HID = 16;
constexpr int BSHIFT = 7;          // 128 dsts per bucket
constexpr int BSIZE = 1 << BSHIFT;
constexpr int CAP = 5120;          // slots per bucket (mean 4096, sigma 64)
constexpr int ECHUNK = 8192;       // edges per scatter block
constexpr int SBLK = 1024;         // scatter/fat block threads

typedef __attribute__((ext_vector_type(8))) short short8;
typedef __attribute__((ext_vector_type(4))) float f32x4;
typedef __attribute__((ext_vector_type(16))) float f32x16;

static __device__ inline short f2bf(float x) {
    __hip_bfloat16 h = __float2bfloat16(x);
    return __builtin_bit_cast(short, h);
}
static __device__ inline float bf2f(unsigned short u) {
    unsigned int x = ((unsigned int)u) << 16;
    return __builtin_bit_cast(float, x);
}

__global__ __launch_bounds__(256) void k_init_curs(int* __restrict__ curs, int nbuck) {
    int b = blockIdx.x * 256 + threadIdx.x;
    if (b < nbuck) curs[b] = b * CAP;
}

// ---------- FAT: LDS counting-sort bin-scatter ∥ MFMA ln_xw1 ∥ prep (all 1024t) ----------
__global__ __launch_bounds__(SBLK) void k_fat(
    const int* __restrict__ src, const int* __restrict__ dst, int E,
    int* __restrict__ curs, int* __restrict__ bin, int nbuck, int nScat,
    const float* __restrict__ x, const float* __restrict__ g, const float* __restrict__ b,
    const float* __restrict__ W1, float* __restrict__ y, int N, int lnBlocks,
    const float* __restrict__ W3, const float* __restrict__ eg, const float* __restrict__ eb,
    const float* __restrict__ b3, short* __restrict__ w3f, float* __restrict__ c12) {
    __shared__ int hist[1024];               // counts -> local cursor
    __shared__ int bstart[1024];             // scan -> diff (runbase - bstart)
    __shared__ unsigned short perm[ECHUNK];  // 16 KB
    __shared__ int dstbuf[ECHUNK];           // 32 KB: dst cached once, reused 2x
    __shared__ int wsum[SBLK / 64];
    int bb = blockIdx.x;
    int t = threadIdx.x;
    if (bb < nScat) {
        // ---- scatter body ----
        int base = bb * ECHUNK;
        int lim = min(ECHUNK, E - base);
        hist[t] = 0;
        __syncthreads();
        for (int i = t; i < lim; i += SBLK) {
            int d = dst[base + i];
            dstbuf[i] = d;
            atomicAdd(&hist[d >> BSHIFT], 1);
        }
        __syncthreads();
        {
            int lane = t & 63, wv = t >> 6;
            int v = hist[t];
            int run = v;
#pragma unroll
            for (int o = 1; o < 64; o <<= 1) {
                int u = __shfl_up(run, o);
                if (lane >= o) run += u;
            }
            if (lane == 63) wsum[wv] = run;
            __syncthreads();
            int wbase = 0;
            for (int w = 0; w < wv; ++w) wbase += wsum[w];
            bstart[t] = wbase + run - v;   // exclusive prefix
        }
        __syncthreads();
        {
            int c = hist[t];
            int bs = bstart[t];
            int rb = (c > 0 && t < nbuck) ? atomicAdd(&curs[t], c) : 0;
            hist[t] = bs;            // cursor for perm build
            bstart[t] = rb - bs;     // diff: global pos = diff + local sorted idx
        }
        __syncthreads();
        for (int i = t; i < lim; i += SBLK) {
            int d = dstbuf[i];
            int pos = atomicAdd(&hist[d >> BSHIFT], 1);
            perm[pos] = (unsigned short)i;
        }
        __syncthreads();
        for (int i = t; i < lim; i += SBLK) {
            int idx = perm[i];
            int d = dstbuf[idx];
            int s = src[base + idx];
            int bk = d >> BSHIFT;
            bin[bstart[bk] + i] = (s << BSHIFT) | (d & (BSIZE - 1));
        }
        return;
    }
    if (bb >= nScat + lnBlocks) {
        // ---- prep block: W3 frags in 32x32x16 A-layout: A[row=n=l&31][k=(l>>5)*8+j] ----
        int l = t;
        if (l >= 64) return;
        int n = l & 31, kh = l >> 5;
#pragma unroll
        for (int c = 0; c < 4; ++c) {
            short8 frag;
#pragma unroll
            for (int j = 0; j < 8; ++j) {
                int k = c * 16 + kh * 8 + j;
                frag[j] = f2bf(eg[k] * W3[k * 32 + n]);
            }
            *(short8*)(w3f + (size_t)(c * 64 + l) * 8) = frag;
        }
        if (l < 32) {
            float s1 = 0.f, s2 = 0.f;
            for (int j = 0; j < 64; ++j) {
                s1 += eg[j] * W3[j * 32 + l];
                s2 += eb[j] * W3[j * 32 + l];
            }
            c12[l] = s1;
            c12[32 + l] = b3[l] + s2;
        }
        return;
    }
    // ---- ln_xw1 via MFMA: 16 waves/block, one wave = 16 nodes ----
    {
        int wv = t >> 6;
        int nb = ((bb - nScat) * 16 + wv) * 16;
        if (nb >= N) return;
        int l = t & 63, gq = l >> 4, r = l & 15;
        int node = nb + r;
        bool ok = node < N;
        const float* xrow = x + (size_t)(ok ? node : 0) * IN_DIM + 8 * gq;
        float xv[4][8];
#pragma unroll
        for (int c = 0; c < 4; ++c) {
            f32x4 p0 = ok ? __builtin_nontemporal_load((const f32x4*)(xrow + 32 * c))
                          : (f32x4){0.f, 0.f, 0.f, 0.f};
            f32x4 p1 = ok ? __builtin_nontemporal_load((const f32x4*)(xrow + 32 * c + 4))
                          : (f32x4){0.f, 0.f, 0.f, 0.f};
            xv[c][0] = p0.x; xv[c][1] = p0.y; xv[c][2] = p0.z; xv[c][3] = p0.w;
            xv[c][4] = p1.x; xv[c][5] = p1.y; xv[c][6] = p1.z; xv[c][7] = p1.w;
        }
        float s = 0.f, q = 0.f;
#pragma unroll
        for (int c = 0; c < 4; ++c)
#pragma unroll
            for (int j = 0; j < 8; ++j) {
                s += xv[c][j];
                q = fmaf(xv[c][j], xv[c][j], q);
            }
        s += __shfl_xor(s, 16); s += __shfl_xor(s, 32);
        q += __shfl_xor(q, 16); q += __shfl_xor(q, 32);
        float mu = s * (1.0f / IN_DIM);
        float var = q * (1.0f / IN_DIM) - mu * mu;
        float rstd = rsqrtf(var + 1e-5f);
        f32x4 acc = {0.f, 0.f, 0.f, 0.f};
#pragma unroll
        for (int c = 0; c < 4; ++c) {
            const float* gp = g + 32 * c + 8 * gq;
            const float* bp = b + 32 * c + 8 * gq;
            const float* wp = W1 + (size_t)(32 * c + 8 * gq) * HID + r;
            short8 A, B;
#pragma unroll
            for (int j = 0; j < 8; ++j) {
                float xn = fmaf((xv[c][j] - mu) * rstd, gp[j], bp[j]);
                A[j] = f2bf(xn);
                B[j] = f2bf(wp[j * HID]);
            }
            acc = __builtin_amdgcn_mfma_f32_16x16x32_bf16(A, B, acc, 0, 0, 0);
        }
#pragma unroll
        for (int reg = 0; reg < 4; ++reg) {
            int n2 = nb + 4 * gq + reg;
            if (n2 < N) y[(size_t)n2 * HID + r] = acc[reg];
        }
    }
}

// ---------- per-bucket (512t): degree, dinv, offs, y-scale->bf16, csr fill ----------
__global__ __launch_bounds__(512) void k_bucket(const int* __restrict__ curs,
                                                const int* __restrict__ bin,
                                                float* __restrict__ dinv,
                                                int* __restrict__ offs,
                                                int* __restrict__ deg,
                                                const float* __restrict__ y,
                                                unsigned short* __restrict__ ybf,
                                                int* __restrict__ csr, int N) {
    __shared__ int cnt[BSIZE];
    __shared__ int scn[BSIZE];
    __shared__ int tmp[BSIZE];
    __shared__ float dl[BSIZE];
    int b = blockIdx.x;
    int t = threadIdx.x;
    int lo = b * CAP;
    int hi = curs[b];
    if (t < BSIZE) cnt[t] = 0;
    __syncthreads();
    for (int i = lo + t; i < hi; i += 512)
        atomicAdd(&cnt[bin[i] & (BSIZE - 1)], 1);
    __syncthreads();
    // parallel exclusive scan of 128 counts (Hillis-Steele)
    if (t < BSIZE) tmp[t] = cnt[t];
    __syncthreads();
#pragma unroll
    for (int o = 1; o < BSIZE; o <<= 1) {
        int v = 0;
        if (t < BSIZE && t >= o) v = tmp[t - o];
        __syncthreads();
        if (t < BSIZE) tmp[t] += v;
        __syncthreads();
    }
    int d0 = b << BSHIFT;
    if (t < BSIZE) {
        scn[t] = lo + tmp[t] - cnt[t];   // exclusive + bucket base
        int d = d0 + t;
        if (d < N) {
            int c = cnt[t];
            float di = rsqrtf((float)(c + 1));
            dl[t] = di;
            dinv[d] = di;
            offs[d] = scn[t];
            deg[d] = c;
        }
    }
    __syncthreads();
    for (int idx = t; idx < BSIZE * HID; idx += 512) {
        int d = d0 + (idx >> 4);
        if (d < N)
            ybf[(size_t)d * HID + (idx & 15)] =
                (unsigned short)f2bf(y[(size_t)d * HID + (idx & 15)] * dl[idx >> 4]);
    }
    for (int i = lo + t; i < hi; i += 512) {
        int v = bin[i];
        int pos = atomicAdd(&scn[v & (BSIZE - 1)], 1);
        csr[pos] = v >> BSHIFT;
    }
}

// ---------- gather1 + xw2 fused, 8-wide pipelined ----------
__global__ __launch_bounds__(256) void k_gather_xw2(const unsigned short* __restrict__ y,
                                                    const float* __restrict__ dinv,
                                                    const float* __restrict__ bias,
                                                    const int* __restrict__ offs,
                                                    const int* __restrict__ deg,
                                                    const int* __restrict__ csr,
                                                    const float* __restrict__ W2,
                                                    unsigned short* __restrict__ y2, int N) {
    int t = blockIdx.x * 256 + threadIdx.x;
    int i = t >> 4, k = t & 15;
    if (i >= N) return;
    int j0 = offs[i], j1 = j0 + deg[i];
    float acc = bf2f(y[(size_t)i * HID + k]);
    int j = j0;
    int c0, c1, c2, c3, c4, c5, c6, c7;
    if (j + 8 <= j1) {
        c0 = csr[j];     c1 = csr[j + 1]; c2 = csr[j + 2]; c3 = csr[j + 3];
        c4 = csr[j + 4]; c5 = csr[j + 5]; c6 = csr[j + 6]; c7 = csr[j + 7];
    }
    while (j + 8 <= j1) {
        int n0 = c0, n1 = c1, n2 = c2, n3 = c3, n4 = c4, n5 = c5, n6 = c6, n7 = c7;
        int jn = j + 8;
        if (jn + 8 <= j1) {
            c0 = csr[jn];     c1 = csr[jn + 1]; c2 = csr[jn + 2]; c3 = csr[jn + 3];
            c4 = csr[jn + 4]; c5 = csr[jn + 5]; c6 = csr[jn + 6]; c7 = csr[jn + 7];
        }
        float a0 = bf2f(y[(size_t)n0 * HID + k]);
        float a1 = bf2f(y[(size_t)n1 * HID + k]);
        float a2 = bf2f(y[(size_t)n2 * HID + k]);
        float a3 = bf2f(y[(size_t)n3 * HID + k]);
        float a4 = bf2f(y[(size_t)n4 * HID + k]);
        float a5 = bf2f(y[(size_t)n5 * HID + k]);
        float a6 = bf2f(y[(size_t)n6 * HID + k]);
        float a7 = bf2f(y[(size_t)n7 * HID + k]);
        acc += ((a0 + a1) + (a2 + a3)) + ((a4 + a5) + (a6 + a7));
        j = jn;
    }
    for (; j < j1; ++j) acc += bf2f(y[(size_t)csr[j] * HID + k]);
    float di = dinv[i];
    float hk = fmaxf(bias[k] + di * acc, 0.0f);
    float acc2 = 0.f;
#pragma unroll
    for (int jj = 0; jj < 16; ++jj)
        acc2 = fmaf(__shfl(hk, jj, 16), W2[jj * 16 + k], acc2);
    y2[(size_t)i * HID + k] = (unsigned short)f2bf(di * acc2);
}

// ---------- gather2, 8-wide pipelined ----------
__global__ __launch_bounds__(256) void k_gather(const unsigned short* __restrict__ y,
                                                const float* __restrict__ dinv,
                                                const float* __restrict__ bias,
                                                const int* __restrict__ offs,
                                                const int* __restrict__ deg,
                                                const int* __restrict__ csr,
                                                unsigned short* __restrict__ h, int N) {
    int t = blockIdx.x * 256 + threadIdx.x;
    int i = t >> 4, k = t & 15;
    if (i >= N) return;
    int j0 = offs[i], j1 = j0 + deg[i];
    float acc = bf2f(y[(size_t)i * HID + k]);
    int j = j0;
    int c0, c1, c2, c3, c4, c5, c6, c7;
    if (j + 8 <= j1) {
        c0 = csr[j];     c1 = csr[j + 1]; c2 = csr[j + 2]; c3 = csr[j + 3];
        c4 = csr[j + 4]; c5 = csr[j + 5]; c6 = csr[j + 6]; c7 = csr[j + 7];
    }
    while (j + 8 <= j1) {
        int n0 = c0, n1 = c1, n2 = c2, n3 = c3, n4 = c4, n5 = c5, n6 = c6, n7 = c7;
        int jn = j + 8;
        if (jn + 8 <= j1) {
            c0 = csr[jn];     c1 = csr[jn + 1]; c2 = csr[jn + 2]; c3 = csr[jn + 3];
            c4 = csr[jn + 4]; c5 = csr[jn + 5]; c6 = csr[jn + 6]; c7 = csr[jn + 7];
        }
        float a0 = bf2f(y[(size_t)n0 * HID + k]);
        float a1 = bf2f(y[(size_t)n1 * HID + k]);
        float a2 = bf2f(y[(size_t)n2 * HID + k]);
        float a3 = bf2f(y[(size_t)n3 * HID + k]);
        float a4 = bf2f(y[(size_t)n4 * HID + k]);
        float a5 = bf2f(y[(size_t)n5 * HID + k]);
        float a6 = bf2f(y[(size_t)n6 * HID + k]);
        float a7 = bf2f(y[(size_t)n7 * HID + k]);
        acc += ((a0 + a1) + (a2 + a3)) + ((a4 + a5) + (a6 + a7));
        j = jn;
    }
    for (; j < j1; ++j) acc += bf2f(y[(size_t)csr[j] * HID + k]);
    h[(size_t)i * HID + k] = (unsigned short)f2bf(fmaxf(bias[k] + dinv[i] * acc, 0.0f));
}

// ---------- Pair MLP via swapped 32x32x16 MFMA: one wave = 32 pairs ----------
__global__ __launch_bounds__(256) void k_pairs(const int* __restrict__ pa,
                                               const int* __restrict__ pb,
                                               const unsigned short* __restrict__ h2,
                                               const short* __restrict__ w3f,
                                               const float* __restrict__ c12,
                                               const float* __restrict__ W4,
                                               const float* __restrict__ b4,
                                               float* __restrict__ out,
                                               int P, int ntiles, int nwaves) {
    int wid = (blockIdx.x * 256 + threadIdx.x) >> 6;
    int l = threadIdx.x & 63;
    int p32 = l & 31;
    int kh = l >> 5;

    short8 wf0 = *(const short8*)(w3f + (size_t)(0 * 64 + l) * 8);
    short8 wf1 = *(const short8*)(w3f + (size_t)(1 * 64 + l) * 8);
    short8 wf2 = *(const short8*)(w3f + (size_t)(2 * 64 + l) * 8);
    short8 wf3 = *(const short8*)(w3f + (size_t)(3 * 64 + l) * 8);
    float c1v[16], c2v[16], w4v[16];
#pragma unroll
    for (int reg = 0; reg < 16; ++reg) {
        int n = (reg & 3) + 8 * (reg >> 2) + 4 * kh;
        c1v[reg] = c12[n];
        c2v[reg] = c12[32 + n];
        w4v[reg] = W4[n];
    }
    float b4v = b4[0];

    auto loadTile = [&](int tl, short8& u, short8& v) {
        u = (short8){0, 0, 0, 0, 0, 0, 0, 0};
        v = u;
        if (tl < ntiles) {
            int p = tl * 32 + p32;
            int pp = (p < P) ? p : 0;
            int ia = __builtin_nontemporal_load(pa + pp);
            int ib = __builtin_nontemporal_load(pb + pp);
            u = *(const short8*)(h2 + (size_t)ia * HID + 8 * kh);
            v = *(const short8*)(h2 + (size_t)ib * HID + 8 * kh);
        }
    };

    short8 ubf, vbf;
    loadTile(wid, ubf, vbf);
    for (int tile = wid; tile < ntiles; tile += nwaves) {
        short8 ubf_n, vbf_n;
        loadTile(tile + nwaves, ubf_n, vbf_n);

        float s = 0.f, q = 0.f;
        short8 B2, B3;
#pragma unroll
        for (int j = 0; j < 8; ++j) {
            float fu = bf2f((unsigned short)ubf[j]);
            float fv = bf2f((unsigned short)vbf[j]);
            float a2 = fabsf(fu - fv);
            float a3 = fu * fv;
            s += (fu + fv) + (a2 + a3);
            q = fmaf(fu, fu, q);
            q = fmaf(fv, fv, q);
            q = fmaf(a2, a2, q);
            q = fmaf(a3, a3, q);
            B2[j] = f2bf(a2);
            B3[j] = f2bf(a3);
        }
        s += __shfl_xor(s, 32);
        q += __shfl_xor(q, 32);
        float mu = s * (1.0f / 64.0f);
        float var = q * (1.0f / 64.0f) - mu * mu;
        float rstd = rsqrtf(var + 1e-5f);

        f32x16 d = {0.f, 0.f, 0.f, 0.f, 0.f, 0.f, 0.f, 0.f,
                    0.f, 0.f, 0.f, 0.f, 0.f, 0.f, 0.f, 0.f};
        d = __builtin_amdgcn_mfma_f32_32x32x16_bf16(wf0, ubf, d, 0, 0, 0);
        d = __builtin_amdgcn_mfma_f32_32x32x16_bf16(wf1, vbf, d, 0, 0, 0);
        d = __builtin_amdgcn_mfma_f32_32x32x16_bf16(wf2, B2, d, 0, 0, 0);
        d = __builtin_amdgcn_mfma_f32_32x32x16_bf16(wf3, B3, d, 0, 0, 0);

        float pr = 0.f;
#pragma unroll
        for (int reg = 0; reg < 16; ++reg) {
            float e = fmaxf(fmaf(rstd, fmaf(-mu, c1v[reg], d[reg]), c2v[reg]), 0.f);
            pr = fmaf(e, w4v[reg], pr);
        }
        pr += __shfl_xor(pr, 32);
        int p = tile * 32 + p32;
        if (l < 32 && p < P) out[p] = pr + b4v;

        ubf = ubf_n;
        vbf = vbf_n;
    }
}

extern "C" void kernel_launch(void* const* d_in, const int* in_sizes, int n_in,
                              void* d_out, int out_size, void* d_ws, size_t ws_size,
                              hipStream_t stream) {
    const float* x    = (const float*)d_in[0];
    const int*   ei   = (const int*)d_in[1];
    const int*   ep   = (const int*)d_in[2];
    const float* ln_g = (const float*)d_in[3];
    const float* ln_b = (const float*)d_in[4];
    const float* W1   = (const float*)d_in[5];
    const float* b1   = (const float*)d_in[6];
    const float* W2   = (const float*)d_in[7];
    const float* b2   = (const float*)d_in[8];
    const float* eg   = (const float*)d_in[9];
    const float* eb   = (const float*)d_in[10];
    const float* W3   = (const float*)d_in[11];
    const float* b3   = (const float*)d_in[12];
    const float* W4   = (const float*)d_in[13];
    const float* b4   = (const float*)d_in[14];
    float* out = (float*)d_out;

    const int N = in_sizes[0] / IN_DIM;
    const int E = in_sizes[1] / 2;
    const int P = in_sizes[2] / 2;
    const int* src = ei;
    const int* dst = ei + E;
    const int* pa = ep;
    const int* pb = ep + P;

    auto cdiv = [](long a, long b) { return (int)((a + b - 1) / b); };
    const int NBUCK = cdiv(N, BSIZE);
    const size_t Na = ((size_t)N + 255) & ~(size_t)255;
    const size_t binSlots = (size_t)NBUCK * CAP;

    // workspace layout
    float*          dinv = (float*)d_ws;                   // Na
    int*            degA = (int*)(dinv + Na);              // Na
    int*            offs = degA + Na;                      // Na
    int*            curs = offs + Na;                      // 1024
    float*          y    = (float*)(curs + 1024);          // N*16 f32 (unscaled)
    unsigned short* ybf  = (unsigned short*)(y + (size_t)N * HID);  // N*16 bf16
    int*            csr  = (int*)(ybf + Na * HID);         // binSlots
    int*            bin  = csr + binSlots;                 // binSlots (dead after k_bucket)
    unsigned short* y2bf = (unsigned short*)bin;           // overlay on bin
    unsigned short* h2bf = y2bf + Na * HID;                // overlay on bin
    short*          w3f  = (short*)(bin + binSlots);       // 2048 shorts
    float*          c12  = (float*)(w3f + 2048);           // 64 floats

    const int nScat = cdiv(E, ECHUNK);       // 391
    const int lnBlocks = cdiv(N, 256);       // 391 (16 waves x 16 nodes per block)

    k_init_curs<<<cdiv(NBUCK, 256), 256, 0, stream>>>(curs, NBUCK);
    k_fat<<<nScat + lnBlocks + 1, SBLK, 0, stream>>>(src, dst, E, curs, bin, NBUCK, nScat,
                                                     x, ln_g, ln_b, W1, y, N, lnBlocks,
                                                     W3, eg, eb, b3, w3f, c12);
    k_bucket<<<NBUCK, 512, 0, stream>>>(curs, bin, dinv, offs, degA, y, ybf, csr, N);
    k_gather_xw2<<<cdiv((long)N * 16, 256), 256, 0, stream>>>(ybf, dinv, b1, offs, degA, csr, W2, y2bf, N);
    k_gather<<<cdiv((long)N * 16, 256), 256, 0, stream>>>(y2bf, dinv, b2, offs, degA, csr, h2bf, N);

    const int ntiles = cdiv(P, 32);
    const int blocks = 2048;
    const int nwaves = blocks * 4;
    k_pairs<<<blocks, 256, 0, stream>>>(pa, pb, h2bf, w3f, c12, W4, b4, out, P, ntiles, nwaves);
}

// Round 19
// 161.274 us; speedup vs baseline: 1.4939x; 1.0671x over previous
//
#include <hip/hip_runtime.h>
#include <hip/hip_bf16.h>

constexpr int IN_DIM = 128;
constexpr int HID = 16;
constexpr int BSHIFT = 7;          // 128 dsts per bucket
constexpr int BSIZE = 1 << BSHIFT;
constexpr int CAP = 5120;          // slots per bucket (mean 4096, sigma 64)
constexpr int ECHUNK = 8192;       // edges per scatter block
constexpr int SBLK = 1024;         // scatter/fat block threads

typedef __attribute__((ext_vector_type(8))) short short8;
typedef __attribute__((ext_vector_type(4))) float f32x4;
typedef __attribute__((ext_vector_type(16))) float f32x16;
typedef __attribute__((ext_vector_type(4))) unsigned short us4;

static __device__ inline short f2bf(float x) {
    __hip_bfloat16 h = __float2bfloat16(x);
    return __builtin_bit_cast(short, h);
}
static __device__ inline float bf2f(unsigned short u) {
    unsigned int x = ((unsigned int)u) << 16;
    return __builtin_bit_cast(float, x);
}

__global__ __launch_bounds__(256) void k_init_curs(int* __restrict__ curs, int nbuck) {
    int b = blockIdx.x * 256 + threadIdx.x;
    if (b < nbuck) curs[b] = b * CAP;
}

// ---------- FAT: LDS counting-sort bin-scatter ∥ MFMA ln_xw1 ∥ prep (all 1024t) ----------
__global__ __launch_bounds__(SBLK) void k_fat(
    const int* __restrict__ src, const int* __restrict__ dst, int E,
    int* __restrict__ curs, int* __restrict__ bin, int nbuck, int nScat,
    const float* __restrict__ x, const float* __restrict__ g, const float* __restrict__ b,
    const float* __restrict__ W1, float* __restrict__ y, int N, int lnBlocks,
    const float* __restrict__ W3, const float* __restrict__ eg, const float* __restrict__ eb,
    const float* __restrict__ b3, short* __restrict__ w3f, float* __restrict__ c12) {
    __shared__ int hist[1024];               // counts -> local cursor
    __shared__ int bstart[1024];             // scan -> diff (runbase - bstart)
    __shared__ unsigned short perm[ECHUNK];  // 16 KB
    __shared__ int pkbuf[ECHUNK];            // 32 KB: packed (s<<7)|(d&127)
    __shared__ unsigned short bkbuf[ECHUNK]; // 16 KB: bucket id
    __shared__ int wsum[SBLK / 64];
    int bb = blockIdx.x;
    int t = threadIdx.x;
    if (bb < nScat) {
        // ---- scatter body: all global reads coalesced in pass 1 ----
        int base = bb * ECHUNK;
        int lim = min(ECHUNK, E - base);
        hist[t] = 0;
        __syncthreads();
        for (int i = t; i < lim; i += SBLK) {
            int d = dst[base + i];
            int s = src[base + i];
            pkbuf[i] = (s << BSHIFT) | (d & (BSIZE - 1));
            bkbuf[i] = (unsigned short)(d >> BSHIFT);
            atomicAdd(&hist[d >> BSHIFT], 1);
        }
        __syncthreads();
        {
            int lane = t & 63, wv = t >> 6;
            int v = hist[t];
            int run = v;
#pragma unroll
            for (int o = 1; o < 64; o <<= 1) {
                int u = __shfl_up(run, o);
                if (lane >= o) run += u;
            }
            if (lane == 63) wsum[wv] = run;
            __syncthreads();
            int wbase = 0;
            for (int w = 0; w < wv; ++w) wbase += wsum[w];
            bstart[t] = wbase + run - v;   // exclusive prefix
        }
        __syncthreads();
        {
            int c = hist[t];
            int bs = bstart[t];
            int rb = (c > 0 && t < nbuck) ? atomicAdd(&curs[t], c) : 0;
            hist[t] = bs;            // cursor for perm build
            bstart[t] = rb - bs;     // diff: global pos = diff + local sorted idx
        }
        __syncthreads();
        for (int i = t; i < lim; i += SBLK) {
            int bk = bkbuf[i];
            int pos = atomicAdd(&hist[bk], 1);
            perm[pos] = (unsigned short)i;
        }
        __syncthreads();
        for (int i = t; i < lim; i += SBLK) {
            int idx = perm[i];
            int bk = bkbuf[idx];
            bin[bstart[bk] + i] = pkbuf[idx];   // pure LDS -> coalesced global
        }
        return;
    }
    if (bb >= nScat + lnBlocks) {
        // ---- prep block: W3 frags in 32x32x16 A-layout: A[row=n=l&31][k=(l>>5)*8+j] ----
        int l = t;
        if (l >= 64) return;
        int n = l & 31, kh = l >> 5;
#pragma unroll
        for (int c = 0; c < 4; ++c) {
            short8 frag;
#pragma unroll
            for (int j = 0; j < 8; ++j) {
                int k = c * 16 + kh * 8 + j;
                frag[j] = f2bf(eg[k] * W3[k * 32 + n]);
            }
            *(short8*)(w3f + (size_t)(c * 64 + l) * 8) = frag;
        }
        if (l < 32) {
            float s1 = 0.f, s2 = 0.f;
            for (int j = 0; j < 64; ++j) {
                s1 += eg[j] * W3[j * 32 + l];
                s2 += eb[j] * W3[j * 32 + l];
            }
            c12[l] = s1;
            c12[32 + l] = b3[l] + s2;
        }
        return;
    }
    // ---- ln_xw1 via MFMA: 16 waves/block, one wave = 16 nodes ----
    {
        int wv = t >> 6;
        int nb = ((bb - nScat) * 16 + wv) * 16;
        if (nb >= N) return;
        int l = t & 63, gq = l >> 4, r = l & 15;
        int node = nb + r;
        bool ok = node < N;
        const float* xrow = x + (size_t)(ok ? node : 0) * IN_DIM + 8 * gq;
        float xv[4][8];
#pragma unroll
        for (int c = 0; c < 4; ++c) {
            f32x4 p0 = ok ? __builtin_nontemporal_load((const f32x4*)(xrow + 32 * c))
                          : (f32x4){0.f, 0.f, 0.f, 0.f};
            f32x4 p1 = ok ? __builtin_nontemporal_load((const f32x4*)(xrow + 32 * c + 4))
                          : (f32x4){0.f, 0.f, 0.f, 0.f};
            xv[c][0] = p0.x; xv[c][1] = p0.y; xv[c][2] = p0.z; xv[c][3] = p0.w;
            xv[c][4] = p1.x; xv[c][5] = p1.y; xv[c][6] = p1.z; xv[c][7] = p1.w;
        }
        float s = 0.f, q = 0.f;
#pragma unroll
        for (int c = 0; c < 4; ++c)
#pragma unroll
            for (int j = 0; j < 8; ++j) {
                s += xv[c][j];
                q = fmaf(xv[c][j], xv[c][j], q);
            }
        s += __shfl_xor(s, 16); s += __shfl_xor(s, 32);
        q += __shfl_xor(q, 16); q += __shfl_xor(q, 32);
        float mu = s * (1.0f / IN_DIM);
        float var = q * (1.0f / IN_DIM) - mu * mu;
        float rstd = rsqrtf(var + 1e-5f);
        f32x4 acc = {0.f, 0.f, 0.f, 0.f};
#pragma unroll
        for (int c = 0; c < 4; ++c) {
            const float* gp = g + 32 * c + 8 * gq;
            const float* bp = b + 32 * c + 8 * gq;
            const float* wp = W1 + (size_t)(32 * c + 8 * gq) * HID + r;
            short8 A, B;
#pragma unroll
            for (int j = 0; j < 8; ++j) {
                float xn = fmaf((xv[c][j] - mu) * rstd, gp[j], bp[j]);
                A[j] = f2bf(xn);
                B[j] = f2bf(wp[j * HID]);
            }
            acc = __builtin_amdgcn_mfma_f32_16x16x32_bf16(A, B, acc, 0, 0, 0);
        }
#pragma unroll
        for (int reg = 0; reg < 4; ++reg) {
            int n2 = nb + 4 * gq + reg;
            if (n2 < N) y[(size_t)n2 * HID + r] = acc[reg];
        }
    }
}

// ---------- per-bucket (512t): degree, dinv, offs, y-scale->bf16, csr fill ----------
__global__ __launch_bounds__(512) void k_bucket(const int* __restrict__ curs,
                                                const int* __restrict__ bin,
                                                float* __restrict__ dinv,
                                                int* __restrict__ offs,
                                                int* __restrict__ deg,
                                                const float* __restrict__ y,
                                                unsigned short* __restrict__ ybf,
                                                int* __restrict__ csr, int N) {
    __shared__ int cnt[BSIZE];
    __shared__ int scn[BSIZE];
    __shared__ int tmp[BSIZE];
    __shared__ float dl[BSIZE];
    int b = blockIdx.x;
    int t = threadIdx.x;
    int lo = b * CAP;
    int hi = curs[b];
    if (t < BSIZE) cnt[t] = 0;
    __syncthreads();
    for (int i = lo + t; i < hi; i += 512)
        atomicAdd(&cnt[bin[i] & (BSIZE - 1)], 1);
    __syncthreads();
    if (t < BSIZE) tmp[t] = cnt[t];
    __syncthreads();
#pragma unroll
    for (int o = 1; o < BSIZE; o <<= 1) {
        int v = 0;
        if (t < BSIZE && t >= o) v = tmp[t - o];
        __syncthreads();
        if (t < BSIZE) tmp[t] += v;
        __syncthreads();
    }
    int d0 = b << BSHIFT;
    if (t < BSIZE) {
        scn[t] = lo + tmp[t] - cnt[t];
        int d = d0 + t;
        if (d < N) {
            int c = cnt[t];
            float di = rsqrtf((float)(c + 1));
            dl[t] = di;
            dinv[d] = di;
            offs[d] = scn[t];
            deg[d] = c;
        }
    }
    __syncthreads();
    for (int idx = t; idx < BSIZE * HID; idx += 512) {
        int d = d0 + (idx >> 4);
        if (d < N)
            ybf[(size_t)d * HID + (idx & 15)] =
                (unsigned short)f2bf(y[(size_t)d * HID + (idx & 15)] * dl[idx >> 4]);
    }
    for (int i = lo + t; i < hi; i += 512) {
        int v = bin[i];
        int pos = atomicAdd(&scn[v & (BSIZE - 1)], 1);
        csr[pos] = v >> BSHIFT;
    }
}

// ---------- gather1 + xw2 fused: 4 lanes/node, 4 channels each, bf16x4 loads ----------
__global__ __launch_bounds__(256) void k_gather_xw2(const unsigned short* __restrict__ y,
                                                    const float* __restrict__ dinv,
                                                    const float* __restrict__ bias,
                                                    const int* __restrict__ offs,
                                                    const int* __restrict__ deg,
                                                    const int* __restrict__ csr,
                                                    const float* __restrict__ W2,
                                                    unsigned short* __restrict__ y2, int N) {
    int t = blockIdx.x * 256 + threadIdx.x;
    int i = t >> 2, c = t & 3;
    if (i >= N) return;
    int j0 = offs[i], j1 = j0 + deg[i];
    us4 self = *(const us4*)(y + (size_t)i * HID + 4 * c);
    float acc[4] = {bf2f(self[0]), bf2f(self[1]), bf2f(self[2]), bf2f(self[3])};
    int j = j0;
    int c0, c1, c2, c3, c4, c5, c6, c7;
    if (j + 8 <= j1) {
        c0 = csr[j];     c1 = csr[j + 1]; c2 = csr[j + 2]; c3 = csr[j + 3];
        c4 = csr[j + 4]; c5 = csr[j + 5]; c6 = csr[j + 6]; c7 = csr[j + 7];
    }
    while (j + 8 <= j1) {
        int n0 = c0, n1 = c1, n2 = c2, n3 = c3, n4 = c4, n5 = c5, n6 = c6, n7 = c7;
        int jn = j + 8;
        if (jn + 8 <= j1) {
            c0 = csr[jn];     c1 = csr[jn + 1]; c2 = csr[jn + 2]; c3 = csr[jn + 3];
            c4 = csr[jn + 4]; c5 = csr[jn + 5]; c6 = csr[jn + 6]; c7 = csr[jn + 7];
        }
        us4 a0 = *(const us4*)(y + (size_t)n0 * HID + 4 * c);
        us4 a1 = *(const us4*)(y + (size_t)n1 * HID + 4 * c);
        us4 a2 = *(const us4*)(y + (size_t)n2 * HID + 4 * c);
        us4 a3 = *(const us4*)(y + (size_t)n3 * HID + 4 * c);
        us4 a4 = *(const us4*)(y + (size_t)n4 * HID + 4 * c);
        us4 a5 = *(const us4*)(y + (size_t)n5 * HID + 4 * c);
        us4 a6 = *(const us4*)(y + (size_t)n6 * HID + 4 * c);
        us4 a7 = *(const us4*)(y + (size_t)n7 * HID + 4 * c);
#pragma unroll
        for (int q = 0; q < 4; ++q) {
            acc[q] += ((bf2f(a0[q]) + bf2f(a1[q])) + (bf2f(a2[q]) + bf2f(a3[q]))) +
                      ((bf2f(a4[q]) + bf2f(a5[q])) + (bf2f(a6[q]) + bf2f(a7[q])));
        }
        j = jn;
    }
    for (; j < j1; ++j) {
        us4 a = *(const us4*)(y + (size_t)csr[j] * HID + 4 * c);
#pragma unroll
        for (int q = 0; q < 4; ++q) acc[q] += bf2f(a[q]);
    }
    float di = dinv[i];
    float hk[4];
#pragma unroll
    for (int q = 0; q < 4; ++q) hk[q] = fmaxf(bias[4 * c + q] + di * acc[q], 0.0f);
    float acc2[4] = {0.f, 0.f, 0.f, 0.f};
#pragma unroll
    for (int cc = 0; cc < 4; ++cc) {
#pragma unroll
        for (int jj = 0; jj < 4; ++jj) {
            float hj = __shfl(hk[jj], cc, 4);
            const float* wrow = W2 + (4 * cc + jj) * 16 + 4 * c;
#pragma unroll
            for (int q = 0; q < 4; ++q) acc2[q] = fmaf(hj, wrow[q], acc2[q]);
        }
    }
    us4 o;
#pragma unroll
    for (int q = 0; q < 4; ++q) o[q] = (unsigned short)f2bf(di * acc2[q]);
    *(us4*)(y2 + (size_t)i * HID + 4 * c) = o;
}

// ---------- gather2: 4 lanes/node, 4 channels each ----------
__global__ __launch_bounds__(256) void k_gather(const unsigned short* __restrict__ y,
                                                const float* __restrict__ dinv,
                                                const float* __restrict__ bias,
                                                const int* __restrict__ offs,
                                                const int* __restrict__ deg,
                                                const int* __restrict__ csr,
                                                unsigned short* __restrict__ h, int N) {
    int t = blockIdx.x * 256 + threadIdx.x;
    int i = t >> 2, c = t & 3;
    if (i >= N) return;
    int j0 = offs[i], j1 = j0 + deg[i];
    us4 self = *(const us4*)(y + (size_t)i * HID + 4 * c);
    float acc[4] = {bf2f(self[0]), bf2f(self[1]), bf2f(self[2]), bf2f(self[3])};
    int j = j0;
    int c0, c1, c2, c3, c4, c5, c6, c7;
    if (j + 8 <= j1) {
        c0 = csr[j];     c1 = csr[j + 1]; c2 = csr[j + 2]; c3 = csr[j + 3];
        c4 = csr[j + 4]; c5 = csr[j + 5]; c6 = csr[j + 6]; c7 = csr[j + 7];
    }
    while (j + 8 <= j1) {
        int n0 = c0, n1 = c1, n2 = c2, n3 = c3, n4 = c4, n5 = c5, n6 = c6, n7 = c7;
        int jn = j + 8;
        if (jn + 8 <= j1) {
            c0 = csr[jn];     c1 = csr[jn + 1]; c2 = csr[jn + 2]; c3 = csr[jn + 3];
            c4 = csr[jn + 4]; c5 = csr[jn + 5]; c6 = csr[jn + 6]; c7 = csr[jn + 7];
        }
        us4 a0 = *(const us4*)(y + (size_t)n0 * HID + 4 * c);
        us4 a1 = *(const us4*)(y + (size_t)n1 * HID + 4 * c);
        us4 a2 = *(const us4*)(y + (size_t)n2 * HID + 4 * c);
        us4 a3 = *(const us4*)(y + (size_t)n3 * HID + 4 * c);
        us4 a4 = *(const us4*)(y + (size_t)n4 * HID + 4 * c);
        us4 a5 = *(const us4*)(y + (size_t)n5 * HID + 4 * c);
        us4 a6 = *(const us4*)(y + (size_t)n6 * HID + 4 * c);
        us4 a7 = *(const us4*)(y + (size_t)n7 * HID + 4 * c);
#pragma unroll
        for (int q = 0; q < 4; ++q) {
            acc[q] += ((bf2f(a0[q]) + bf2f(a1[q])) + (bf2f(a2[q]) + bf2f(a3[q]))) +
                      ((bf2f(a4[q]) + bf2f(a5[q])) + (bf2f(a6[q]) + bf2f(a7[q])));
        }
        j = jn;
    }
    for (; j < j1; ++j) {
        us4 a = *(const us4*)(y + (size_t)csr[j] * HID + 4 * c);
#pragma unroll
        for (int q = 0; q < 4; ++q) acc[q] += bf2f(a[q]);
    }
    float di = dinv[i];
    us4 o;
#pragma unroll
    for (int q = 0; q < 4; ++q)
        o[q] = (unsigned short)f2bf(fmaxf(bias[4 * c + q] + di * acc[q], 0.0f));
    *(us4*)(h + (size_t)i * HID + 4 * c) = o;
}

// ---------- Pair MLP via swapped 32x32x16 MFMA: one wave = 32 pairs ----------
__global__ __launch_bounds__(256) void k_pairs(const int* __restrict__ pa,
                                               const int* __restrict__ pb,
                                               const unsigned short* __restrict__ h2,
                                               const short* __restrict__ w3f,
                                               const float* __restrict__ c12,
                                               const float* __restrict__ W4,
                                               const float* __restrict__ b4,
                                               float* __restrict__ out,
                                               int P, int ntiles, int nwaves) {
    int wid = (blockIdx.x * 256 + threadIdx.x) >> 6;
    int l = threadIdx.x & 63;
    int p32 = l & 31;
    int kh = l >> 5;

    short8 wf0 = *(const short8*)(w3f + (size_t)(0 * 64 + l) * 8);
    short8 wf1 = *(const short8*)(w3f + (size_t)(1 * 64 + l) * 8);
    short8 wf2 = *(const short8*)(w3f + (size_t)(2 * 64 + l) * 8);
    short8 wf3 = *(const short8*)(w3f + (size_t)(3 * 64 + l) * 8);
    float c1v[16], c2v[16], w4v[16];
#pragma unroll
    for (int reg = 0; reg < 16; ++reg) {
        int n = (reg & 3) + 8 * (reg >> 2) + 4 * kh;
        c1v[reg] = c12[n];
        c2v[reg] = c12[32 + n];
        w4v[reg] = W4[n];
    }
    float b4v = b4[0];

    auto loadTile = [&](int tl, short8& u, short8& v) {
        u = (short8){0, 0, 0, 0, 0, 0, 0, 0};
        v = u;
        if (tl < ntiles) {
            int p = tl * 32 + p32;
            int pp = (p < P) ? p : 0;
            int ia = __builtin_nontemporal_load(pa + pp);
            int ib = __builtin_nontemporal_load(pb + pp);
            u = *(const short8*)(h2 + (size_t)ia * HID + 8 * kh);
            v = *(const short8*)(h2 + (size_t)ib * HID + 8 * kh);
        }
    };

    short8 ubf, vbf;
    loadTile(wid, ubf, vbf);
    for (int tile = wid; tile < ntiles; tile += nwaves) {
        short8 ubf_n, vbf_n;
        loadTile(tile + nwaves, ubf_n, vbf_n);

        float s = 0.f, q = 0.f;
        short8 B2, B3;
#pragma unroll
        for (int j = 0; j < 8; ++j) {
            float fu = bf2f((unsigned short)ubf[j]);
            float fv = bf2f((unsigned short)vbf[j]);
            float a2 = fabsf(fu - fv);
            float a3 = fu * fv;
            s += (fu + fv) + (a2 + a3);
            q = fmaf(fu, fu, q);
            q = fmaf(fv, fv, q);
            q = fmaf(a2, a2, q);
            q = fmaf(a3, a3, q);
            B2[j] = f2bf(a2);
            B3[j] = f2bf(a3);
        }
        s += __shfl_xor(s, 32);
        q += __shfl_xor(q, 32);
        float mu = s * (1.0f / 64.0f);
        float var = q * (1.0f / 64.0f) - mu * mu;
        float rstd = rsqrtf(var + 1e-5f);

        f32x16 d = {0.f, 0.f, 0.f, 0.f, 0.f, 0.f, 0.f, 0.f,
                    0.f, 0.f, 0.f, 0.f, 0.f, 0.f, 0.f, 0.f};
        d = __builtin_amdgcn_mfma_f32_32x32x16_bf16(wf0, ubf, d, 0, 0, 0);
        d = __builtin_amdgcn_mfma_f32_32x32x16_bf16(wf1, vbf, d, 0, 0, 0);
        d = __builtin_amdgcn_mfma_f32_32x32x16_bf16(wf2, B2, d, 0, 0, 0);
        d = __builtin_amdgcn_mfma_f32_32x32x16_bf16(wf3, B3, d, 0, 0, 0);

        float pr = 0.f;
#pragma unroll
        for (int reg = 0; reg < 16; ++reg) {
            float e = fmaxf(fmaf(rstd, fmaf(-mu, c1v[reg], d[reg]), c2v[reg]), 0.f);
            pr = fmaf(e, w4v[reg], pr);
        }
        pr += __shfl_xor(pr, 32);
        int p = tile * 32 + p32;
        if (l < 32 && p < P) out[p] = pr + b4v;

        ubf = ubf_n;
        vbf = vbf_n;
    }
}

extern "C" void kernel_launch(void* const* d_in, const int* in_sizes, int n_in,
                              void* d_out, int out_size, void* d_ws, size_t ws_size,
                              hipStream_t stream) {
    const float* x    = (const float*)d_in[0];
    const int*   ei   = (const int*)d_in[1];
    const int*   ep   = (const int*)d_in[2];
    const float* ln_g = (const float*)d_in[3];
    const float* ln_b = (const float*)d_in[4];
    const float* W1   = (const float*)d_in[5];
    const float* b1   = (const float*)d_in[6];
    const float* W2   = (const float*)d_in[7];
    const float* b2   = (const float*)d_in[8];
    const float* eg   = (const float*)d_in[9];
    const float* eb   = (const float*)d_in[10];
    const float* W3   = (const float*)d_in[11];
    const float* b3   = (const float*)d_in[12];
    const float* W4   = (const float*)d_in[13];
    const float* b4   = (const float*)d_in[14];
    float* out = (float*)d_out;

    const int N = in_sizes[0] / IN_DIM;
    const int E = in_sizes[1] / 2;
    const int P = in_sizes[2] / 2;
    const int* src = ei;
    const int* dst = ei + E;
    const int* pa = ep;
    const int* pb = ep + P;

    auto cdiv = [](long a, long b) { return (int)((a + b - 1) / b); };
    const int NBUCK = cdiv(N, BSIZE);
    const size_t Na = ((size_t)N + 255) & ~(size_t)255;
    const size_t binSlots = (size_t)NBUCK * CAP;

    // workspace layout
    float*          dinv = (float*)d_ws;                   // Na
    int*            degA = (int*)(dinv + Na);              // Na
    int*            offs = degA + Na;                      // Na
    int*            curs = offs + Na;                      // 1024
    float*          y    = (float*)(curs + 1024);          // N*16 f32 (unscaled)
    unsigned short* ybf  = (unsigned short*)(y + (size_t)N * HID);  // N*16 bf16
    int*            csr  = (int*)(ybf + Na * HID);         // binSlots
    int*            bin  = csr + binSlots;                 // binSlots (dead after k_bucket)
    unsigned short* y2bf = (unsigned short*)bin;           // overlay on bin
    unsigned short* h2bf = y2bf + Na * HID;                // overlay on bin
    short*          w3f  = (short*)(bin + binSlots);       // 2048 shorts
    float*          c12  = (float*)(w3f + 2048);           // 64 floats

    const int nScat = cdiv(E, ECHUNK);       // 391
    const int lnBlocks = cdiv(N, 256);       // 391 (16 waves x 16 nodes per block)

    k_init_curs<<<cdiv(NBUCK, 256), 256, 0, stream>>>(curs, NBUCK);
    k_fat<<<nScat + lnBlocks + 1, SBLK, 0, stream>>>(src, dst, E, curs, bin, NBUCK, nScat,
                                                     x, ln_g, ln_b, W1, y, N, lnBlocks,
                                                     W3, eg, eb, b3, w3f, c12);
    k_bucket<<<NBUCK, 512, 0, stream>>>(curs, bin, dinv, offs, degA, y, ybf, csr, N);
    k_gather_xw2<<<cdiv((long)N * 4, 256), 256, 0, stream>>>(ybf, dinv, b1, offs, degA, csr, W2, y2bf, N);
    k_gather<<<cdiv((long)N * 4, 256), 256, 0, stream>>>(y2bf, dinv, b2, offs, degA, csr, h2bf, N);

    const int ntiles = cdiv(P, 32);
    const int blocks = 2048;
    const int nwaves = blocks * 4;
    k_pairs<<<blocks, 256, 0, stream>>>(pa, pb, h2bf, w3f, c12, W4, b4, out, P, ntiles, nwaves);
}